// Round 2
// baseline (675.492 us; speedup 1.0000x reference)
//
#include <hip/hip_runtime.h>

// Problem constants
#define S_LEN 4096
#define HID   2048
#define NHQ   8
#define NKV   4
#define DHEAD 256
#define WIN   1024

typedef __attribute__((ext_vector_type(4))) float   floatx4;
typedef __attribute__((ext_vector_type(8))) __bf16  bf16x8;

__device__ __forceinline__ unsigned short f2bf(float f){
  unsigned int u = __float_as_uint(f);
  u += 0x7FFFu + ((u >> 16) & 1u);           // RNE
  return (unsigned short)(u >> 16);
}
__device__ __forceinline__ float bf2f(unsigned short h){
  return __uint_as_float(((unsigned int)h) << 16);
}

// async global->LDS, 16B per lane; LDS base wave-uniform (HW scatters lane i at base+i*16)
__device__ __forceinline__ void gld_lds16(const void* g, void* l){
  __builtin_amdgcn_global_load_lds((const __attribute__((address_space(1))) void*)g,
                                   (__attribute__((address_space(3))) void*)l, 16, 0, 0);
}

// ---------------- converts ----------------
__global__ __launch_bounds__(256) void cvt_f32_bf16(const float* __restrict__ src,
                                                    unsigned short* __restrict__ dst){
  size_t i = ((size_t)blockIdx.x * 256 + threadIdx.x) * 4;
  float4 v = *(const float4*)(src + i);
  *(ushort4*)(dst + i) = make_ushort4(f2bf(v.x), f2bf(v.y), f2bf(v.z), f2bf(v.w));
}

// split hi/lo: x = bf16(x) + bf16(x - hi) (residual ~2^-18 relative)
__global__ __launch_bounds__(256) void cvt_split(const float* __restrict__ src,
                                                 unsigned short* __restrict__ hi,
                                                 unsigned short* __restrict__ lo){
  size_t i = ((size_t)blockIdx.x * 256 + threadIdx.x) * 4;
  float4 v = *(const float4*)(src + i);
  float a[4] = {v.x, v.y, v.z, v.w};
  ushort4 h, l;
  unsigned short hh[4], ll[4];
#pragma unroll
  for (int j = 0; j < 4; ++j){
    hh[j] = f2bf(a[j]);
    ll[j] = f2bf(a[j] - bf2f(hh[j]));
  }
  *(ushort4*)(hi + i) = make_ushort4(hh[0], hh[1], hh[2], hh[3]);
  *(ushort4*)(lo + i) = make_ushort4(ll[0], ll[1], ll[2], ll[3]);
}

// gather Wq(2048)|Wk(1024)|Wv(1024) rows, each [*,2048], into [4096][2048] hi/lo bf16
__global__ __launch_bounds__(256) void cvt_wqkv_split(const float* __restrict__ Wq,
                                                      const float* __restrict__ Wk,
                                                      const float* __restrict__ Wv,
                                                      unsigned short* __restrict__ hi,
                                                      unsigned short* __restrict__ lo){
  size_t i = ((size_t)blockIdx.x * 256 + threadIdx.x) * 4;
  int row = (int)(i >> 11);
  int col = (int)(i & 2047);
  const float* src = (row < 2048) ? (Wq + ((size_t)row << 11))
                   : (row < 3072) ? (Wk + ((size_t)(row - 2048) << 11))
                                  : (Wv + ((size_t)(row - 3072) << 11));
  float4 v = *(const float4*)(src + col);
  float a[4] = {v.x, v.y, v.z, v.w};
  unsigned short hh[4], ll[4];
#pragma unroll
  for (int j = 0; j < 4; ++j){
    hh[j] = f2bf(a[j]);
    ll[j] = f2bf(a[j] - bf2f(hh[j]));
  }
  *(ushort4*)(hi + i) = make_ushort4(hh[0], hh[1], hh[2], hh[3]);
  *(ushort4*)(lo + i) = make_ushort4(ll[0], ll[1], ll[2], ll[3]);
}

// ---------------- 3-product split NT GEMM (emulated fp32): C = (Ah+Al)(Bh+Bl)^T ----------------
// 128x128 tile, BK=32, 256 thr = 2x2 waves, 4x4 frags/wave; C fp32.
__global__ __launch_bounds__(256, 2) void gemm3_bt(const unsigned short* __restrict__ Ah,
                                                   const unsigned short* __restrict__ Al,
                                                   const unsigned short* __restrict__ Bh,
                                                   const unsigned short* __restrict__ Bl,
                                                   float* __restrict__ C,
                                                   int M, int N, int K){
  __shared__ __align__(16) unsigned short Ash[128*32], Asl[128*32];
  __shared__ __align__(16) unsigned short Bsh[128*32], Bsl[128*32];   // 32 KB total
  const int t = threadIdx.x, w = t >> 6, lane = t & 63;
  const int quad = lane >> 4, l15 = lane & 15;
  const int l2 = lane >> 2, g8 = (lane & 3) * 8;
  const int wm = w >> 1, wn = w & 1;
  const int bm0 = blockIdx.y * 128, bn0 = blockIdx.x * 128;

  const floatx4 zf = {0.f, 0.f, 0.f, 0.f};
  floatx4 acc[4][4];
#pragma unroll
  for (int mi = 0; mi < 4; ++mi)
#pragma unroll
    for (int ni = 0; ni < 4; ++ni) acc[mi][ni] = zf;

  for (int k0 = 0; k0 < K; k0 += 32){
#pragma unroll
    for (int j = 0; j < 2; ++j){
      int ch  = j * 4 + w;                  // 0..7 chunks of 1KB
      int row = ch * 16 + l2;
      size_t offA = (size_t)(bm0 + row) * K + k0 + g8;
      size_t offB = (size_t)(bn0 + row) * K + k0 + g8;
      gld_lds16(Ah + offA, &Ash[ch * 512]);
      gld_lds16(Al + offA, &Asl[ch * 512]);
      gld_lds16(Bh + offB, &Bsh[ch * 512]);
      gld_lds16(Bl + offB, &Bsl[ch * 512]);
    }
    __syncthreads();
    bf16x8 afh[4], afl[4], bfh[4], bfl[4];
#pragma unroll
    for (int mi = 0; mi < 4; ++mi){
      afh[mi] = *(const bf16x8*)&Ash[(wm*64 + mi*16 + l15)*32 + quad*8];
      afl[mi] = *(const bf16x8*)&Asl[(wm*64 + mi*16 + l15)*32 + quad*8];
    }
#pragma unroll
    for (int ni = 0; ni < 4; ++ni){
      bfh[ni] = *(const bf16x8*)&Bsh[(wn*64 + ni*16 + l15)*32 + quad*8];
      bfl[ni] = *(const bf16x8*)&Bsl[(wn*64 + ni*16 + l15)*32 + quad*8];
    }
#pragma unroll
    for (int mi = 0; mi < 4; ++mi)
#pragma unroll
      for (int ni = 0; ni < 4; ++ni){
        acc[mi][ni] = __builtin_amdgcn_mfma_f32_16x16x32_bf16(afh[mi], bfh[ni], acc[mi][ni], 0, 0, 0);
        acc[mi][ni] = __builtin_amdgcn_mfma_f32_16x16x32_bf16(afh[mi], bfl[ni], acc[mi][ni], 0, 0, 0);
        acc[mi][ni] = __builtin_amdgcn_mfma_f32_16x16x32_bf16(afl[mi], bfh[ni], acc[mi][ni], 0, 0, 0);
      }
    __syncthreads();
  }
#pragma unroll
  for (int mi = 0; mi < 4; ++mi)
#pragma unroll
    for (int ni = 0; ni < 4; ++ni)
#pragma unroll
      for (int r = 0; r < 4; ++r){
        int m = bm0 + wm*64 + mi*16 + quad*4 + r;
        int n = bn0 + wn*64 + ni*16 + l15;
        C[(size_t)m * N + n] = acc[mi][ni][r];
      }
}

// ---------------- single-precision bf16 NT GEMM (out-projection) ----------------
__global__ __launch_bounds__(256, 2) void gemm_bt(const unsigned short* __restrict__ A,
                                                  const unsigned short* __restrict__ B,
                                                  float* __restrict__ C,
                                                  int M, int N, int K){
  __shared__ __align__(16) unsigned short As[128 * 32];
  __shared__ __align__(16) unsigned short Bs[128 * 32];
  const int t = threadIdx.x, w = t >> 6, lane = t & 63;
  const int quad = lane >> 4, l15 = lane & 15;
  const int l2 = lane >> 2, g8 = (lane & 3) * 8;
  const int wm = w >> 1, wn = w & 1;
  const int bm0 = blockIdx.y * 128, bn0 = blockIdx.x * 128;

  const floatx4 zf = {0.f, 0.f, 0.f, 0.f};
  floatx4 acc[4][4];
#pragma unroll
  for (int mi = 0; mi < 4; ++mi)
#pragma unroll
    for (int ni = 0; ni < 4; ++ni) acc[mi][ni] = zf;

  for (int k0 = 0; k0 < K; k0 += 32){
#pragma unroll
    for (int j = 0; j < 2; ++j){
      int ch  = j * 4 + w;
      int row = ch * 16 + l2;
      gld_lds16(A + (size_t)(bm0 + row) * K + k0 + g8, &As[ch * 512]);
      gld_lds16(B + (size_t)(bn0 + row) * K + k0 + g8, &Bs[ch * 512]);
    }
    __syncthreads();
    bf16x8 af[4], bf[4];
#pragma unroll
    for (int mi = 0; mi < 4; ++mi) af[mi] = *(const bf16x8*)&As[(wm*64 + mi*16 + l15)*32 + quad*8];
#pragma unroll
    for (int ni = 0; ni < 4; ++ni) bf[ni] = *(const bf16x8*)&Bs[(wn*64 + ni*16 + l15)*32 + quad*8];
#pragma unroll
    for (int mi = 0; mi < 4; ++mi)
#pragma unroll
      for (int ni = 0; ni < 4; ++ni)
        acc[mi][ni] = __builtin_amdgcn_mfma_f32_16x16x32_bf16(af[mi], bf[ni], acc[mi][ni], 0, 0, 0);
    __syncthreads();
  }
#pragma unroll
  for (int mi = 0; mi < 4; ++mi)
#pragma unroll
    for (int ni = 0; ni < 4; ++ni)
#pragma unroll
      for (int r = 0; r < 4; ++r){
        int m = bm0 + wm*64 + mi*16 + quad*4 + r;
        int n = bn0 + wn*64 + ni*16 + l15;
        C[(size_t)m * N + n] = acc[mi][ni][r];
      }
}

// ---------------- RMSNorm + RoPE post-process (fp32 in, split bf16 out for Q/K) ----------------
// one wave per (token s, head hh); hh 0..7 = Q, 8..11 = K, 12..15 = V
__global__ __launch_bounds__(256) void qkv_post(const float* __restrict__ qkvf,
                                                const float* __restrict__ cosb,
                                                const float* __restrict__ sinb,
                                                const float* __restrict__ qnw,
                                                const float* __restrict__ knw,
                                                unsigned short* __restrict__ Qh,
                                                unsigned short* __restrict__ Ql,
                                                unsigned short* __restrict__ Kh,
                                                unsigned short* __restrict__ Kl,
                                                unsigned short* __restrict__ Vo){
  int gw   = blockIdx.x * 4 + (threadIdx.x >> 6);
  int lane = threadIdx.x & 63;
  int hh = gw & 15, s = gw >> 4;
  int colbase = (hh < 8) ? hh * 256 : (hh < 12 ? 2048 + (hh - 8) * 256 : 3072 + (hh - 12) * 256);

  float4 raw = *(const float4*)(qkvf + (size_t)s * 4096 + colbase + lane * 4);
  float x0 = raw.x, x1 = raw.y, x2 = raw.z, x3 = raw.w;
  float ss = x0*x0 + x1*x1 + x2*x2 + x3*x3;
#pragma unroll
  for (int off = 32; off; off >>= 1) ss += __shfl_xor(ss, off);
  float inv = rsqrtf(ss * (1.0f / 256.0f) + 1e-6f);

  if (hh < 12){
    const float* wp = (hh < 8) ? qnw : knw;
    float4 wv = *(const float4*)(wp + lane * 4);
    float y[4] = { x0*inv*wv.x, x1*inv*wv.y, x2*inv*wv.z, x3*inv*wv.w };
    float4 cv = *(const float4*)(cosb + (size_t)s * 256 + lane * 4);
    float4 sv = *(const float4*)(sinb + (size_t)s * 256 + lane * 4);
    float cj[4] = {cv.x, cv.y, cv.z, cv.w};
    float sj[4] = {sv.x, sv.y, sv.z, sv.w};
    unsigned short oh[4], ol[4];
#pragma unroll
    for (int j = 0; j < 4; ++j){
      float oth = __shfl_xor(y[j], 32);          // element d +/- 128
      float rot = (lane < 32) ? -oth : oth;      // rot = [-x2, x1]
      float o = y[j] * cj[j] + rot * sj[j];
      oh[j] = f2bf(o);
      ol[j] = f2bf(o - bf2f(oh[j]));
    }
    ushort4 rh = make_ushort4(oh[0], oh[1], oh[2], oh[3]);
    ushort4 rl = make_ushort4(ol[0], ol[1], ol[2], ol[3]);
    if (hh < 8){
      size_t o = (size_t)(hh * S_LEN + s) * DHEAD + lane * 4;
      *(ushort4*)(Qh + o) = rh;  *(ushort4*)(Ql + o) = rl;
    } else {
      size_t o = (size_t)((hh - 8) * S_LEN + s) * DHEAD + lane * 4;
      *(ushort4*)(Kh + o) = rh;  *(ushort4*)(Kl + o) = rl;
    }
  } else {
    ushort4 r = make_ushort4(f2bf(x0*inv), f2bf(x1*inv), f2bf(x2*inv), f2bf(x3*inv));
    *(ushort4*)(Vo + (size_t)((hh - 12) * S_LEN + s) * DHEAD + lane * 4) = r;
  }
}

// ---------------- V transpose: [kv][s][256] -> [kv][d][4096] ----------------
__global__ __launch_bounds__(256) void transpose_v(const unsigned short* __restrict__ v,
                                                   unsigned short* __restrict__ vt){
  __shared__ unsigned short tile[64][68];
  int kv = blockIdx.z, d0 = blockIdx.x * 64, s0 = blockIdx.y * 64;
  int t = threadIdx.x;
  int r = t >> 4, c4 = (t & 15) * 4;
#pragma unroll
  for (int i = 0; i < 4; ++i){
    int row = r + i * 16;
    ushort4 xx = *(const ushort4*)(v + (size_t)(kv * S_LEN + s0 + row) * DHEAD + d0 + c4);
    tile[row][c4] = xx.x; tile[row][c4+1] = xx.y; tile[row][c4+2] = xx.z; tile[row][c4+3] = xx.w;
  }
  __syncthreads();
#pragma unroll
  for (int i = 0; i < 4; ++i){
    int dr = r + i * 16;
    ushort4 yy = make_ushort4(tile[c4][dr], tile[c4+1][dr], tile[c4+2][dr], tile[c4+3][dr]);
    *(ushort4*)(vt + (size_t)(kv * DHEAD + d0 + dr) * S_LEN + s0 + c4) = yy;
  }
}

// ---------------- sliding-window softcapped flash attention (split-precision QK^T) ----------------
// grid (32, 8): 128 queries/block, 4 waves x 32 rows; 32-key tiles.
__global__ __launch_bounds__(256, 1) void attn_win(const unsigned short* __restrict__ Qhh,
                                                   const unsigned short* __restrict__ Qll,
                                                   const unsigned short* __restrict__ Khh,
                                                   const unsigned short* __restrict__ Kll,
                                                   const unsigned short* __restrict__ Vt,
                                                   unsigned short* __restrict__ Og){
  __shared__ __align__(16) unsigned short Ksh[8 * 32 * 32];  // 16 KB
  __shared__ __align__(16) unsigned short Ksl[8 * 32 * 32];  // 16 KB
  __shared__ __align__(16) unsigned short Vts[256 * 32];     // 16 KB
  __shared__ __align__(16) unsigned short Pb[4][32 * 48];    // 12 KB

  const int h = blockIdx.y, kv = h >> 1;
  const int q0 = blockIdx.x * 128;
  const int t = threadIdx.x, w = t >> 6, lane = t & 63;
  const int quad = lane >> 4, l15 = lane & 15;
  const int l2 = lane >> 2, g8 = (lane & 3) * 8;
  const int qw0 = q0 + w * 32;

  bf16x8 qfh[2][8], qfl[2][8];
#pragma unroll
  for (int mi = 0; mi < 2; ++mi)
#pragma unroll
    for (int c = 0; c < 8; ++c){
      size_t o = (size_t)(h * S_LEN + qw0 + mi*16 + l15) * DHEAD + c*32 + quad*8;
      qfh[mi][c] = *(const bf16x8*)(Qhh + o);
      qfl[mi][c] = *(const bf16x8*)(Qll + o);
    }

  const floatx4 zf = {0.f, 0.f, 0.f, 0.f};
  floatx4 oacc[2][16];
#pragma unroll
  for (int mi = 0; mi < 2; ++mi)
#pragma unroll
    for (int dt = 0; dt < 16; ++dt) oacc[mi][dt] = zf;
  float m_run[2][4], l_run[2][4];
#pragma unroll
  for (int mi = 0; mi < 2; ++mi)
#pragma unroll
    for (int r = 0; r < 4; ++r){ m_run[mi][r] = -50.0f; l_run[mi][r] = 0.0f; } // softcap bounds logits

  int kt_lo = q0 / 32 - 32; if (kt_lo < 0) kt_lo = 0;
  int kt_hi = q0 / 32 + 3;

  for (int kt = kt_lo; kt <= kt_hi; ++kt){
    const int key0 = kt * 32;
    // stage K hi/lo: 16 chunks each; chunk = 16 key-rows of one 32-d block
#pragma unroll
    for (int j = 0; j < 4; ++j){
      int ch = j * 4 + w;                        // 0..15
      int krow = (ch & 1) * 16 + l2;
      int cb = ch >> 1;
      size_t o = (size_t)(kv * S_LEN + key0 + krow) * DHEAD + cb * 32 + g8;
      gld_lds16(Khh + o, &Ksh[ch * 512]);
      gld_lds16(Kll + o, &Ksl[ch * 512]);
      int drow = ch * 16 + l2;
      gld_lds16(Vt + (size_t)(kv * DHEAD + drow) * S_LEN + key0 + g8, &Vts[ch * 512]);
    }
    __syncthreads();

    if (key0 <= qw0 + 31 && key0 + 31 >= qw0 - (WIN - 1)){
      // QK^T: 3-product split, 96 MFMA
      floatx4 sc[2][2];
      sc[0][0] = zf; sc[0][1] = zf; sc[1][0] = zf; sc[1][1] = zf;
#pragma unroll
      for (int c = 0; c < 8; ++c){
#pragma unroll
        for (int nt = 0; nt < 2; ++nt){
          bf16x8 kfh = *(const bf16x8*)&Ksh[c * 1024 + (nt*16 + l15) * 32 + quad * 8];
          bf16x8 kfl = *(const bf16x8*)&Ksl[c * 1024 + (nt*16 + l15) * 32 + quad * 8];
#pragma unroll
          for (int mi = 0; mi < 2; ++mi){
            sc[mi][nt] = __builtin_amdgcn_mfma_f32_16x16x32_bf16(qfh[mi][c], kfh, sc[mi][nt], 0, 0, 0);
            sc[mi][nt] = __builtin_amdgcn_mfma_f32_16x16x32_bf16(qfh[mi][c], kfl, sc[mi][nt], 0, 0, 0);
            sc[mi][nt] = __builtin_amdgcn_mfma_f32_16x16x32_bf16(qfl[mi][c], kfh, sc[mi][nt], 0, 0, 0);
          }
        }
      }
      const bool tfull = (key0 + 31 <= qw0) && (qw0 + 31 - key0 < WIN);
      float x[2][2][4];
#pragma unroll
      for (int mi = 0; mi < 2; ++mi)
#pragma unroll
        for (int nt = 0; nt < 2; ++nt)
#pragma unroll
          for (int r = 0; r < 4; ++r){
            float v = sc[mi][nt][r];
            float e = __expf(v * 0.04f);         // 50*tanh(v/50) = 50 - 100/(e^{0.04v}+1)
            v = 50.0f - 100.0f / (e + 1.0f);
            if (!tfull){
              int qi = qw0 + mi*16 + quad*4 + r;
              int ki = key0 + nt*16 + l15;
              bool ok = (ki <= qi) && (qi - ki < WIN);
              v = ok ? v : -__builtin_inff();
            }
            x[mi][nt][r] = v;
          }
      // online softmax (rows live in 16-lane groups -> xor shuffles 1,2,4,8)
      float alpha[2][4];
#pragma unroll
      for (int mi = 0; mi < 2; ++mi)
#pragma unroll
        for (int r = 0; r < 4; ++r){
          float tm = fmaxf(x[mi][0][r], x[mi][1][r]);
          tm = fmaxf(tm, __shfl_xor(tm, 1));
          tm = fmaxf(tm, __shfl_xor(tm, 2));
          tm = fmaxf(tm, __shfl_xor(tm, 4));
          tm = fmaxf(tm, __shfl_xor(tm, 8));
          float mo = m_run[mi][r];
          float mn = fmaxf(mo, tm);
          float a = __expf(mo - mn);
          m_run[mi][r] = mn; alpha[mi][r] = a;
          float p0 = __expf(x[mi][0][r] - mn);
          float p1 = __expf(x[mi][1][r] - mn);
          x[mi][0][r] = p0; x[mi][1][r] = p1;
          float ls = p0 + p1;
          ls += __shfl_xor(ls, 1);
          ls += __shfl_xor(ls, 2);
          ls += __shfl_xor(ls, 4);
          ls += __shfl_xor(ls, 8);
          l_run[mi][r] = l_run[mi][r] * a + ls;
        }
      // P: D-layout -> LDS -> A-operand layout
#pragma unroll
      for (int mi = 0; mi < 2; ++mi)
#pragma unroll
        for (int nt = 0; nt < 2; ++nt)
#pragma unroll
          for (int r = 0; r < 4; ++r)
            Pb[w][(mi*16 + quad*4 + r) * 48 + nt*16 + l15] = f2bf(x[mi][nt][r]);
      // rescale O
#pragma unroll
      for (int mi = 0; mi < 2; ++mi)
#pragma unroll
        for (int dt = 0; dt < 16; ++dt){
          floatx4 v = oacc[mi][dt];
          v.x *= alpha[mi][0]; v.y *= alpha[mi][1]; v.z *= alpha[mi][2]; v.w *= alpha[mi][3];
          oacc[mi][dt] = v;
        }
      // PV: 32 MFMA
      bf16x8 pf0 = *(const bf16x8*)&Pb[w][(l15) * 48 + quad * 8];
      bf16x8 pf1 = *(const bf16x8*)&Pb[w][(16 + l15) * 48 + quad * 8];
#pragma unroll
      for (int dt = 0; dt < 16; ++dt){
        bf16x8 vf = *(const bf16x8*)&Vts[(dt*16 + l15) * 32 + quad * 8];
        oacc[0][dt] = __builtin_amdgcn_mfma_f32_16x16x32_bf16(pf0, vf, oacc[0][dt], 0, 0, 0);
        oacc[1][dt] = __builtin_amdgcn_mfma_f32_16x16x32_bf16(pf1, vf, oacc[1][dt], 0, 0, 0);
      }
    }
    __syncthreads();
  }
  // epilogue: O[s][h*256+d]
#pragma unroll
  for (int mi = 0; mi < 2; ++mi)
#pragma unroll
    for (int r = 0; r < 4; ++r){
      float rl = 1.0f / l_run[mi][r];
      int srow = qw0 + mi*16 + quad*4 + r;
#pragma unroll
      for (int dt = 0; dt < 16; ++dt)
        Og[(size_t)srow * (NHQ * DHEAD) + h * DHEAD + dt*16 + l15] = f2bf(oacc[mi][dt][r] * rl);
    }
}

// ---------------- launch ----------------
extern "C" void kernel_launch(void* const* d_in, const int* in_sizes, int n_in,
                              void* d_out, int out_size, void* d_ws, size_t ws_size,
                              hipStream_t stream){
  const float* hs   = (const float*)d_in[0];
  const float* cosb = (const float*)d_in[1];
  const float* sinb = (const float*)d_in[2];
  // d_in[3] = attention_mask: structure known (0 <= q-k < 1024), never read
  const float* Wq   = (const float*)d_in[4];
  const float* Wk   = (const float*)d_in[5];
  const float* Wv   = (const float*)d_in[6];
  const float* Wo   = (const float*)d_in[7];
  const float* qnw  = (const float*)d_in[8];
  const float* knw  = (const float*)d_in[9];
  float* out = (float*)d_out;

  const size_t MB = 1024ull * 1024ull;
  char* ws = (char*)d_ws;
  unsigned short* h_hi  = (unsigned short*)(ws);             // 16 MB [4096][2048]
  unsigned short* h_lo  = (unsigned short*)(ws + 16  * MB);  // 16 MB
  unsigned short* w_hi  = (unsigned short*)(ws + 32  * MB);  // 16 MB [4096][2048]
  unsigned short* w_lo  = (unsigned short*)(ws + 48  * MB);  // 16 MB
  unsigned short* wo    = (unsigned short*)(ws + 64  * MB);  //  8 MB [2048][2048]
  float*          qkvf  = (float*)        (ws + 72  * MB);   // 64 MB [4096][4096] fp32
  // after QKV GEMM, h_*/w_* (0..64MB) are dead -> Q/K/V live there
  unsigned short* Qh    = (unsigned short*)(ws);             // 16 MB [8][4096][256]
  unsigned short* Ql    = (unsigned short*)(ws + 16  * MB);  // 16 MB
  unsigned short* Kh    = (unsigned short*)(ws + 32  * MB);  //  8 MB [4][4096][256]
  unsigned short* Kl    = (unsigned short*)(ws + 40  * MB);  //  8 MB
  unsigned short* vb    = (unsigned short*)(ws + 48  * MB);  //  8 MB [4][4096][256]
  // after qkv_post, qkvf (72..136MB) is dead -> Vt and attention output live there
  unsigned short* vt    = (unsigned short*)(ws + 72  * MB);  //  8 MB [4][256][4096]
  unsigned short* ob    = (unsigned short*)(ws + 88  * MB);  // 16 MB [4096][2048]

  cvt_split     <<<8192, 256, 0, stream>>>(hs, h_hi, h_lo);
  cvt_wqkv_split<<<8192, 256, 0, stream>>>(Wq, Wk, Wv, w_hi, w_lo);
  cvt_f32_bf16  <<<4096, 256, 0, stream>>>(Wo, wo);

  gemm3_bt<<<dim3(32, 32), 256, 0, stream>>>(h_hi, h_lo, w_hi, w_lo, qkvf, 4096, 4096, 2048);

  qkv_post<<<16384, 256, 0, stream>>>(qkvf, cosb, sinb, qnw, knw, Qh, Ql, Kh, Kl, vb);
  transpose_v<<<dim3(4, 64, 4), 256, 0, stream>>>(vb, vt);

  attn_win<<<dim3(32, 8), 256, 0, stream>>>(Qh, Ql, Kh, Kl, vt, ob);

  gemm_bt<<<dim3(16, 32), 256, 0, stream>>>(ob, wo, out, 4096, 2048, 2048);
}

// Round 3
// 570.886 us; speedup vs baseline: 1.1832x; 1.1832x over previous
//
#include <hip/hip_runtime.h>

#define S_LEN 4096
#define HID   2048
#define NHQ   8
#define NKV   4
#define DHEAD 256
#define WIN   1024

typedef __attribute__((ext_vector_type(4))) float   floatx4;
typedef __attribute__((ext_vector_type(8))) __bf16  bf16x8;

__device__ __forceinline__ unsigned short f2bf(float f){
  unsigned int u = __float_as_uint(f);
  u += 0x7FFFu + ((u >> 16) & 1u);           // RNE
  return (unsigned short)(u >> 16);
}
__device__ __forceinline__ float bf2f(unsigned short h){
  return __uint_as_float(((unsigned int)h) << 16);
}

__device__ __forceinline__ void gld_lds16(const void* g, void* l){
  __builtin_amdgcn_global_load_lds((const __attribute__((address_space(1))) void*)g,
                                   (__attribute__((address_space(3))) void*)l, 16, 0, 0);
}

// ---------------- merged converts ----------------
// bid < 8192: split(hs); bid < 16384: split(Wqkv gathered); else: plain bf16(Wo)
__global__ __launch_bounds__(256) void cvt_all(const float* __restrict__ hs,
                                               const float* __restrict__ Wq,
                                               const float* __restrict__ Wk,
                                               const float* __restrict__ Wv,
                                               const float* __restrict__ Wo,
                                               unsigned short* __restrict__ h_hi,
                                               unsigned short* __restrict__ h_lo,
                                               unsigned short* __restrict__ w_hi,
                                               unsigned short* __restrict__ w_lo,
                                               unsigned short* __restrict__ wo){
  int bid = blockIdx.x;
  if (bid < 8192){
    size_t i = ((size_t)bid * 256 + threadIdx.x) * 4;
    float4 v = *(const float4*)(hs + i);
    float a[4] = {v.x, v.y, v.z, v.w};
    unsigned short hh[4], ll[4];
#pragma unroll
    for (int j = 0; j < 4; ++j){ hh[j] = f2bf(a[j]); ll[j] = f2bf(a[j] - bf2f(hh[j])); }
    *(ushort4*)(h_hi + i) = make_ushort4(hh[0], hh[1], hh[2], hh[3]);
    *(ushort4*)(h_lo + i) = make_ushort4(ll[0], ll[1], ll[2], ll[3]);
  } else if (bid < 16384){
    size_t i = ((size_t)(bid - 8192) * 256 + threadIdx.x) * 4;
    int row = (int)(i >> 11), col = (int)(i & 2047);
    const float* src = (row < 2048) ? (Wq + ((size_t)row << 11))
                     : (row < 3072) ? (Wk + ((size_t)(row - 2048) << 11))
                                    : (Wv + ((size_t)(row - 3072) << 11));
    float4 v = *(const float4*)(src + col);
    float a[4] = {v.x, v.y, v.z, v.w};
    unsigned short hh[4], ll[4];
#pragma unroll
    for (int j = 0; j < 4; ++j){ hh[j] = f2bf(a[j]); ll[j] = f2bf(a[j] - bf2f(hh[j])); }
    *(ushort4*)(w_hi + i) = make_ushort4(hh[0], hh[1], hh[2], hh[3]);
    *(ushort4*)(w_lo + i) = make_ushort4(ll[0], ll[1], ll[2], ll[3]);
  } else {
    size_t i = ((size_t)(bid - 16384) * 256 + threadIdx.x) * 4;
    float4 v = *(const float4*)(Wo + i);
    *(ushort4*)(wo + i) = make_ushort4(f2bf(v.x), f2bf(v.y), f2bf(v.z), f2bf(v.w));
  }
}

// ---------------- 3-product split NT GEMM: C[m][n] (fp32, ldC) = (Ah+Al)(Bh+Bl)^T ----------------
__global__ __launch_bounds__(256, 2) void gemm3_bt(const unsigned short* __restrict__ Ah,
                                                   const unsigned short* __restrict__ Al,
                                                   const unsigned short* __restrict__ Bh,
                                                   const unsigned short* __restrict__ Bl,
                                                   float* __restrict__ C,
                                                   int ldC, int K){
  __shared__ __align__(16) unsigned short Ash[128*32], Asl[128*32];
  __shared__ __align__(16) unsigned short Bsh[128*32], Bsl[128*32];
  const int t = threadIdx.x, w = t >> 6, lane = t & 63;
  const int quad = lane >> 4, l15 = lane & 15;
  const int l2 = lane >> 2, g8 = (lane & 3) * 8;
  const int wm = w >> 1, wn = w & 1;
  const int bm0 = blockIdx.y * 128, bn0 = blockIdx.x * 128;

  const floatx4 zf = {0.f, 0.f, 0.f, 0.f};
  floatx4 acc[4][4];
#pragma unroll
  for (int mi = 0; mi < 4; ++mi)
#pragma unroll
    for (int ni = 0; ni < 4; ++ni) acc[mi][ni] = zf;

  for (int k0 = 0; k0 < K; k0 += 32){
#pragma unroll
    for (int j = 0; j < 2; ++j){
      int ch  = j * 4 + w;
      int row = ch * 16 + l2;
      size_t offA = (size_t)(bm0 + row) * K + k0 + g8;
      size_t offB = (size_t)(bn0 + row) * K + k0 + g8;
      gld_lds16(Ah + offA, &Ash[ch * 512]);
      gld_lds16(Al + offA, &Asl[ch * 512]);
      gld_lds16(Bh + offB, &Bsh[ch * 512]);
      gld_lds16(Bl + offB, &Bsl[ch * 512]);
    }
    __syncthreads();
    bf16x8 afh[4], afl[4], bfh[4], bfl[4];
#pragma unroll
    for (int mi = 0; mi < 4; ++mi){
      afh[mi] = *(const bf16x8*)&Ash[(wm*64 + mi*16 + l15)*32 + quad*8];
      afl[mi] = *(const bf16x8*)&Asl[(wm*64 + mi*16 + l15)*32 + quad*8];
    }
#pragma unroll
    for (int ni = 0; ni < 4; ++ni){
      bfh[ni] = *(const bf16x8*)&Bsh[(wn*64 + ni*16 + l15)*32 + quad*8];
      bfl[ni] = *(const bf16x8*)&Bsl[(wn*64 + ni*16 + l15)*32 + quad*8];
    }
#pragma unroll
    for (int mi = 0; mi < 4; ++mi)
#pragma unroll
      for (int ni = 0; ni < 4; ++ni){
        acc[mi][ni] = __builtin_amdgcn_mfma_f32_16x16x32_bf16(afh[mi], bfh[ni], acc[mi][ni], 0, 0, 0);
        acc[mi][ni] = __builtin_amdgcn_mfma_f32_16x16x32_bf16(afh[mi], bfl[ni], acc[mi][ni], 0, 0, 0);
        acc[mi][ni] = __builtin_amdgcn_mfma_f32_16x16x32_bf16(afl[mi], bfh[ni], acc[mi][ni], 0, 0, 0);
      }
    __syncthreads();
  }
#pragma unroll
  for (int mi = 0; mi < 4; ++mi)
#pragma unroll
    for (int ni = 0; ni < 4; ++ni)
#pragma unroll
      for (int r = 0; r < 4; ++r){
        int m = bm0 + wm*64 + mi*16 + quad*4 + r;
        int n = bn0 + wn*64 + ni*16 + l15;
        C[(size_t)m * ldC + n] = acc[mi][ni][r];
      }
}

// ---------------- plain bf16 NT GEMM -> fp32 C (ldC) ----------------
__global__ __launch_bounds__(256, 2) void gemm_bt(const unsigned short* __restrict__ A,
                                                  const unsigned short* __restrict__ B,
                                                  float* __restrict__ C,
                                                  int ldC, int K){
  __shared__ __align__(16) unsigned short As[128 * 32];
  __shared__ __align__(16) unsigned short Bs[128 * 32];
  const int t = threadIdx.x, w = t >> 6, lane = t & 63;
  const int quad = lane >> 4, l15 = lane & 15;
  const int l2 = lane >> 2, g8 = (lane & 3) * 8;
  const int wm = w >> 1, wn = w & 1;
  const int bm0 = blockIdx.y * 128, bn0 = blockIdx.x * 128;

  const floatx4 zf = {0.f, 0.f, 0.f, 0.f};
  floatx4 acc[4][4];
#pragma unroll
  for (int mi = 0; mi < 4; ++mi)
#pragma unroll
    for (int ni = 0; ni < 4; ++ni) acc[mi][ni] = zf;

  for (int k0 = 0; k0 < K; k0 += 32){
#pragma unroll
    for (int j = 0; j < 2; ++j){
      int ch  = j * 4 + w;
      int row = ch * 16 + l2;
      gld_lds16(A + (size_t)(bm0 + row) * K + k0 + g8, &As[ch * 512]);
      gld_lds16(B + (size_t)(bn0 + row) * K + k0 + g8, &Bs[ch * 512]);
    }
    __syncthreads();
    bf16x8 af[4], bf[4];
#pragma unroll
    for (int mi = 0; mi < 4; ++mi) af[mi] = *(const bf16x8*)&As[(wm*64 + mi*16 + l15)*32 + quad*8];
#pragma unroll
    for (int ni = 0; ni < 4; ++ni) bf[ni] = *(const bf16x8*)&Bs[(wn*64 + ni*16 + l15)*32 + quad*8];
#pragma unroll
    for (int mi = 0; mi < 4; ++mi)
#pragma unroll
      for (int ni = 0; ni < 4; ++ni)
        acc[mi][ni] = __builtin_amdgcn_mfma_f32_16x16x32_bf16(af[mi], bf[ni], acc[mi][ni], 0, 0, 0);
    __syncthreads();
  }
#pragma unroll
  for (int mi = 0; mi < 4; ++mi)
#pragma unroll
    for (int ni = 0; ni < 4; ++ni)
#pragma unroll
      for (int r = 0; r < 4; ++r){
        int m = bm0 + wm*64 + mi*16 + quad*4 + r;
        int n = bn0 + wn*64 + ni*16 + l15;
        C[(size_t)m * ldC + n] = acc[mi][ni][r];
      }
}

// ---------------- RMSNorm + RoPE post-process (fp32 in, split bf16 out for Q/K) ----------------
__global__ __launch_bounds__(256) void qkv_post(const float* __restrict__ qkvf,
                                                const float* __restrict__ cosb,
                                                const float* __restrict__ sinb,
                                                const float* __restrict__ qnw,
                                                const float* __restrict__ knw,
                                                unsigned short* __restrict__ Qh,
                                                unsigned short* __restrict__ Ql,
                                                unsigned short* __restrict__ Kh,
                                                unsigned short* __restrict__ Kl,
                                                unsigned short* __restrict__ Vo){
  int gw   = blockIdx.x * 4 + (threadIdx.x >> 6);
  int lane = threadIdx.x & 63;
  int hh = gw & 15, s = gw >> 4;
  int colbase = (hh < 8) ? hh * 256 : (hh < 12 ? 2048 + (hh - 8) * 256 : 3072 + (hh - 12) * 256);

  float4 raw = *(const float4*)(qkvf + (size_t)s * 4096 + colbase + lane * 4);
  float x0 = raw.x, x1 = raw.y, x2 = raw.z, x3 = raw.w;
  float ss = x0*x0 + x1*x1 + x2*x2 + x3*x3;
#pragma unroll
  for (int off = 32; off; off >>= 1) ss += __shfl_xor(ss, off);
  float inv = rsqrtf(ss * (1.0f / 256.0f) + 1e-6f);

  if (hh < 12){
    const float* wp = (hh < 8) ? qnw : knw;
    float4 wv = *(const float4*)(wp + lane * 4);
    float y[4] = { x0*inv*wv.x, x1*inv*wv.y, x2*inv*wv.z, x3*inv*wv.w };
    float4 cv = *(const float4*)(cosb + (size_t)s * 256 + lane * 4);
    float4 sv = *(const float4*)(sinb + (size_t)s * 256 + lane * 4);
    float cj[4] = {cv.x, cv.y, cv.z, cv.w};
    float sj[4] = {sv.x, sv.y, sv.z, sv.w};
    unsigned short oh[4], ol[4];
#pragma unroll
    for (int j = 0; j < 4; ++j){
      float oth = __shfl_xor(y[j], 32);          // element d +/- 128
      float rot = (lane < 32) ? -oth : oth;      // rot = [-x2, x1]
      float o = y[j] * cj[j] + rot * sj[j];
      oh[j] = f2bf(o);
      ol[j] = f2bf(o - bf2f(oh[j]));
    }
    ushort4 rh = make_ushort4(oh[0], oh[1], oh[2], oh[3]);
    ushort4 rl = make_ushort4(ol[0], ol[1], ol[2], ol[3]);
    if (hh < 8){
      size_t o = (size_t)(hh * S_LEN + s) * DHEAD + lane * 4;
      *(ushort4*)(Qh + o) = rh;  *(ushort4*)(Ql + o) = rl;
    } else {
      size_t o = (size_t)((hh - 8) * S_LEN + s) * DHEAD + lane * 4;
      *(ushort4*)(Kh + o) = rh;  *(ushort4*)(Kl + o) = rl;
    }
  } else {
    ushort4 r = make_ushort4(f2bf(x0*inv), f2bf(x1*inv), f2bf(x2*inv), f2bf(x3*inv));
    *(ushort4*)(Vo + (size_t)((hh - 12) * S_LEN + s) * DHEAD + lane * 4) = r;
  }
}

// ---------------- V transpose: [kv][s][256] -> [kv][d][4096] ----------------
__global__ __launch_bounds__(256) void transpose_v(const unsigned short* __restrict__ v,
                                                   unsigned short* __restrict__ vt){
  __shared__ unsigned short tile[64][68];
  int kv = blockIdx.z, d0 = blockIdx.x * 64, s0 = blockIdx.y * 64;
  int t = threadIdx.x;
  int r = t >> 4, c4 = (t & 15) * 4;
#pragma unroll
  for (int i = 0; i < 4; ++i){
    int row = r + i * 16;
    ushort4 xx = *(const ushort4*)(v + (size_t)(kv * S_LEN + s0 + row) * DHEAD + d0 + c4);
    tile[row][c4] = xx.x; tile[row][c4+1] = xx.y; tile[row][c4+2] = xx.z; tile[row][c4+3] = xx.w;
  }
  __syncthreads();
#pragma unroll
  for (int i = 0; i < 4; ++i){
    int dr = r + i * 16;
    ushort4 yy = make_ushort4(tile[c4][dr], tile[c4+1][dr], tile[c4+2][dr], tile[c4+3][dr]);
    *(ushort4*)(vt + (size_t)(kv * DHEAD + d0 + dr) * S_LEN + s0 + c4) = yy;
  }
}

// ---------------- sliding-window softcapped flash attention ----------------
// v2: 64 queries/block (4 waves x 16 rows), grid (64, 8) = 512 blocks -> 2 blocks/CU.
__global__ __launch_bounds__(256, 2) void attn_win(const unsigned short* __restrict__ Qhh,
                                                   const unsigned short* __restrict__ Qll,
                                                   const unsigned short* __restrict__ Khh,
                                                   const unsigned short* __restrict__ Kll,
                                                   const unsigned short* __restrict__ Vt,
                                                   unsigned short* __restrict__ Og){
  __shared__ __align__(16) unsigned short Ksh[8 * 32 * 32];  // 16 KB
  __shared__ __align__(16) unsigned short Ksl[8 * 32 * 32];  // 16 KB
  __shared__ __align__(16) unsigned short Vts[256 * 32];     // 16 KB
  __shared__ __align__(16) unsigned short Pb[4][16 * 48];    //  6 KB

  const int h = blockIdx.y, kv = h >> 1;
  const int q0 = blockIdx.x * 64;
  const int t = threadIdx.x, w = t >> 6, lane = t & 63;
  const int quad = lane >> 4, l15 = lane & 15;
  const int l2 = lane >> 2, g8 = (lane & 3) * 8;
  const int qw0 = q0 + w * 16;

  bf16x8 qfh[8], qfl[8];
#pragma unroll
  for (int c = 0; c < 8; ++c){
    size_t o = (size_t)(h * S_LEN + qw0 + l15) * DHEAD + c*32 + quad*8;
    qfh[c] = *(const bf16x8*)(Qhh + o);
    qfl[c] = *(const bf16x8*)(Qll + o);
  }

  const floatx4 zf = {0.f, 0.f, 0.f, 0.f};
  floatx4 oacc[16];
#pragma unroll
  for (int dt = 0; dt < 16; ++dt) oacc[dt] = zf;
  float m_run[4], l_run[4];
#pragma unroll
  for (int r = 0; r < 4; ++r){ m_run[r] = -50.0f; l_run[r] = 0.0f; }  // softcap bounds logits

  int kt_lo = q0 / 32 - 32; if (kt_lo < 0) kt_lo = 0;
  int kt_hi = q0 / 32 + 1;

  for (int kt = kt_lo; kt <= kt_hi; ++kt){
    const int key0 = kt * 32;
#pragma unroll
    for (int j = 0; j < 4; ++j){
      int ch = j * 4 + w;                        // 0..15
      int krow = (ch & 1) * 16 + l2;
      int cb = ch >> 1;
      size_t o = (size_t)(kv * S_LEN + key0 + krow) * DHEAD + cb * 32 + g8;
      gld_lds16(Khh + o, &Ksh[ch * 512]);
      gld_lds16(Kll + o, &Ksl[ch * 512]);
      int drow = ch * 16 + l2;
      gld_lds16(Vt + (size_t)(kv * DHEAD + drow) * S_LEN + key0 + g8, &Vts[ch * 512]);
    }
    __syncthreads();

    if (key0 <= qw0 + 15 && key0 + 31 >= qw0 - (WIN - 1)){
      // QK^T: 3-product split, 48 MFMA
      floatx4 sc[2];
      sc[0] = zf; sc[1] = zf;
#pragma unroll
      for (int c = 0; c < 8; ++c){
#pragma unroll
        for (int nt = 0; nt < 2; ++nt){
          bf16x8 kfh = *(const bf16x8*)&Ksh[c * 1024 + (nt*16 + l15) * 32 + quad * 8];
          bf16x8 kfl = *(const bf16x8*)&Ksl[c * 1024 + (nt*16 + l15) * 32 + quad * 8];
          sc[nt] = __builtin_amdgcn_mfma_f32_16x16x32_bf16(qfh[c], kfh, sc[nt], 0, 0, 0);
          sc[nt] = __builtin_amdgcn_mfma_f32_16x16x32_bf16(qfh[c], kfl, sc[nt], 0, 0, 0);
          sc[nt] = __builtin_amdgcn_mfma_f32_16x16x32_bf16(qfl[c], kfh, sc[nt], 0, 0, 0);
        }
      }
      const bool tfull = (key0 + 31 <= qw0) && (qw0 + 15 - key0 < WIN);
      float x[2][4];
#pragma unroll
      for (int nt = 0; nt < 2; ++nt)
#pragma unroll
        for (int r = 0; r < 4; ++r){
          float v = sc[nt][r];
          float e = __expf(v * 0.04f);           // 50*tanh(v/50) = 50 - 100/(e^{0.04v}+1)
          v = 50.0f - 100.0f / (e + 1.0f);
          if (!tfull){
            int qi = qw0 + quad*4 + r;
            int ki = key0 + nt*16 + l15;
            bool ok = (ki <= qi) && (qi - ki < WIN);
            v = ok ? v : -__builtin_inff();
          }
          x[nt][r] = v;
        }
      // online softmax (rows in 16-lane groups -> xor shuffles 1,2,4,8)
      float alpha[4];
#pragma unroll
      for (int r = 0; r < 4; ++r){
        float tm = fmaxf(x[0][r], x[1][r]);
        tm = fmaxf(tm, __shfl_xor(tm, 1));
        tm = fmaxf(tm, __shfl_xor(tm, 2));
        tm = fmaxf(tm, __shfl_xor(tm, 4));
        tm = fmaxf(tm, __shfl_xor(tm, 8));
        float mo = m_run[r];
        float mn = fmaxf(mo, tm);
        float a = __expf(mo - mn);
        m_run[r] = mn; alpha[r] = a;
        float p0 = __expf(x[0][r] - mn);
        float p1 = __expf(x[1][r] - mn);
        x[0][r] = p0; x[1][r] = p1;
        float ls = p0 + p1;
        ls += __shfl_xor(ls, 1);
        ls += __shfl_xor(ls, 2);
        ls += __shfl_xor(ls, 4);
        ls += __shfl_xor(ls, 8);
        l_run[r] = l_run[r] * a + ls;
      }
      // P: D-layout -> LDS -> A-operand layout
#pragma unroll
      for (int nt = 0; nt < 2; ++nt)
#pragma unroll
        for (int r = 0; r < 4; ++r)
          Pb[w][(quad*4 + r) * 48 + nt*16 + l15] = f2bf(x[nt][r]);
      // rescale O
#pragma unroll
      for (int dt = 0; dt < 16; ++dt){
        floatx4 v = oacc[dt];
        v.x *= alpha[0]; v.y *= alpha[1]; v.z *= alpha[2]; v.w *= alpha[3];
        oacc[dt] = v;
      }
      // PV: 16 MFMA
      bf16x8 pf = *(const bf16x8*)&Pb[w][l15 * 48 + quad * 8];
#pragma unroll
      for (int dt = 0; dt < 16; ++dt){
        bf16x8 vf = *(const bf16x8*)&Vts[(dt*16 + l15) * 32 + quad * 8];
        oacc[dt] = __builtin_amdgcn_mfma_f32_16x16x32_bf16(pf, vf, oacc[dt], 0, 0, 0);
      }
    }
    __syncthreads();
  }
#pragma unroll
  for (int r = 0; r < 4; ++r){
    float rl = 1.0f / l_run[r];
    int srow = qw0 + quad*4 + r;
#pragma unroll
    for (int dt = 0; dt < 16; ++dt)
      Og[(size_t)srow * (NHQ * DHEAD) + h * DHEAD + dt*16 + l15] = f2bf(oacc[dt][r] * rl);
  }
}

// ---------------- launch ----------------
extern "C" void kernel_launch(void* const* d_in, const int* in_sizes, int n_in,
                              void* d_out, int out_size, void* d_ws, size_t ws_size,
                              hipStream_t stream){
  const float* hs   = (const float*)d_in[0];
  const float* cosb = (const float*)d_in[1];
  const float* sinb = (const float*)d_in[2];
  // d_in[3] = attention_mask: structure known (0 <= q-k < 1024), never read
  const float* Wq   = (const float*)d_in[4];
  const float* Wk   = (const float*)d_in[5];
  const float* Wv   = (const float*)d_in[6];
  const float* Wo   = (const float*)d_in[7];
  const float* qnw  = (const float*)d_in[8];
  const float* knw  = (const float*)d_in[9];
  float* out = (float*)d_out;

  const size_t MB = 1024ull * 1024ull;
  char* ws = (char*)d_ws;
  unsigned short* h_hi  = (unsigned short*)(ws);             // 16 MB [4096][2048]
  unsigned short* h_lo  = (unsigned short*)(ws + 16  * MB);  // 16 MB
  unsigned short* w_hi  = (unsigned short*)(ws + 32  * MB);  // 16 MB [4096][2048]
  unsigned short* w_lo  = (unsigned short*)(ws + 48  * MB);  // 16 MB
  unsigned short* wo    = (unsigned short*)(ws + 64  * MB);  //  8 MB [2048][2048]
  float*          qkvf  = (float*)        (ws + 72  * MB);   // 64 MB [4096][4096] fp32
  // after QKV GEMMs, h_*/w_* are dead -> Q/K/V live there
  unsigned short* Qh    = (unsigned short*)(ws);             // 16 MB [8][4096][256]
  unsigned short* Ql    = (unsigned short*)(ws + 16  * MB);  // 16 MB
  unsigned short* Kh    = (unsigned short*)(ws + 32  * MB);  //  8 MB [4][4096][256]
  unsigned short* Kl    = (unsigned short*)(ws + 40  * MB);  //  8 MB
  unsigned short* vb    = (unsigned short*)(ws + 48  * MB);  //  8 MB [4][4096][256]
  // after qkv_post, qkvf is dead -> Vt and attention output live there
  unsigned short* vt    = (unsigned short*)(ws + 72  * MB);  //  8 MB [4][256][4096]
  unsigned short* ob    = (unsigned short*)(ws + 88  * MB);  // 16 MB [4096][2048]

  cvt_all<<<20480, 256, 0, stream>>>(hs, Wq, Wk, Wv, Wo, h_hi, h_lo, w_hi, w_lo, wo);

  // Q,K (cols 0..3071): split 3-product; V (cols 3072..4095): plain bf16
  gemm3_bt<<<dim3(24, 32), 256, 0, stream>>>(h_hi, h_lo, w_hi, w_lo, qkvf, 4096, 2048);
  gemm_bt <<<dim3(8, 32),  256, 0, stream>>>(h_hi, w_hi + (size_t)3072 * 2048, qkvf + 3072, 4096, 2048);

  qkv_post<<<16384, 256, 0, stream>>>(qkvf, cosb, sinb, qnw, knw, Qh, Ql, Kh, Kl, vb);
  transpose_v<<<dim3(4, 64, 4), 256, 0, stream>>>(vb, vt);

  attn_win<<<dim3(64, 8), 256, 0, stream>>>(Qh, Ql, Kh, Kl, vt, ob);

  gemm_bt<<<dim3(16, 32), 256, 0, stream>>>(ob, wo, out, 2048, 2048);
}

// Round 4
// 444.194 us; speedup vs baseline: 1.5207x; 1.2852x over previous
//
#include <hip/hip_runtime.h>

#define S_LEN 4096
#define HID   2048
#define NHQ   8
#define NKV   4
#define DHEAD 256
#define WIN   1024

typedef __attribute__((ext_vector_type(4))) float     floatx4;
typedef __attribute__((ext_vector_type(8))) _Float16  halfx8;

__device__ __forceinline__ unsigned short f2h(float f){
  union { _Float16 h; unsigned short u; } cv; cv.h = (_Float16)f; return cv.u;
}
__device__ __forceinline__ float h2f(unsigned short u){
  union { unsigned short u; _Float16 h; } cv; cv.u = u; return (float)cv.h;
}

__device__ __forceinline__ void gld_lds16(const void* g, void* l){
  __builtin_amdgcn_global_load_lds((const __attribute__((address_space(1))) void*)g,
                                   (__attribute__((address_space(3))) void*)l, 16, 0, 0);
}

// ---------------- merged converts (all fp32 -> fp16) ----------------
// bid < 8192: hs; bid < 16384: Wqkv gathered; else: Wo
__global__ __launch_bounds__(256) void cvt_all(const float* __restrict__ hs,
                                               const float* __restrict__ Wq,
                                               const float* __restrict__ Wk,
                                               const float* __restrict__ Wv,
                                               const float* __restrict__ Wo,
                                               unsigned short* __restrict__ h_h,
                                               unsigned short* __restrict__ w_qkv,
                                               unsigned short* __restrict__ wo){
  int bid = blockIdx.x;
  const float* src;
  unsigned short* dst;
  size_t i;
  if (bid < 8192){
    i = ((size_t)bid * 256 + threadIdx.x) * 4;
    src = hs + i; dst = h_h + i;
  } else if (bid < 16384){
    i = ((size_t)(bid - 8192) * 256 + threadIdx.x) * 4;
    int row = (int)(i >> 11), col = (int)(i & 2047);
    src = ((row < 2048) ? (Wq + ((size_t)row << 11))
         : (row < 3072) ? (Wk + ((size_t)(row - 2048) << 11))
                        : (Wv + ((size_t)(row - 3072) << 11))) + col;
    dst = w_qkv + i;
  } else {
    i = ((size_t)(bid - 16384) * 256 + threadIdx.x) * 4;
    src = Wo + i; dst = wo + i;
  }
  float4 v = *(const float4*)src;
  *(ushort4*)dst = make_ushort4(f2h(v.x), f2h(v.y), f2h(v.z), f2h(v.w));
}

// ---------------- fp16 NT GEMM: C[m][n] = A[M,K] * B[N,K]^T ----------------
// 128x128 tile, BK=32, 256 thr = 2x2 waves, 4x4 frags/wave. OUT_F32: fp32 C else fp16 C.
template<int OUT_F32>
__global__ __launch_bounds__(256, 2) void gemm_ht(const unsigned short* __restrict__ A,
                                                  const unsigned short* __restrict__ B,
                                                  void* __restrict__ Cv,
                                                  int ldC, int K){
  __shared__ __align__(16) unsigned short As[128 * 32];
  __shared__ __align__(16) unsigned short Bs[128 * 32];
  const int t = threadIdx.x, w = t >> 6, lane = t & 63;
  const int quad = lane >> 4, l15 = lane & 15;
  const int l2 = lane >> 2, g8 = (lane & 3) * 8;
  const int wm = w >> 1, wn = w & 1;
  const int bm0 = blockIdx.y * 128, bn0 = blockIdx.x * 128;

  const floatx4 zf = {0.f, 0.f, 0.f, 0.f};
  floatx4 acc[4][4];
#pragma unroll
  for (int mi = 0; mi < 4; ++mi)
#pragma unroll
    for (int ni = 0; ni < 4; ++ni) acc[mi][ni] = zf;

  for (int k0 = 0; k0 < K; k0 += 32){
#pragma unroll
    for (int j = 0; j < 2; ++j){
      int ch  = j * 4 + w;
      int row = ch * 16 + l2;
      gld_lds16(A + (size_t)(bm0 + row) * K + k0 + g8, &As[ch * 512]);
      gld_lds16(B + (size_t)(bn0 + row) * K + k0 + g8, &Bs[ch * 512]);
    }
    __syncthreads();
    halfx8 af[4], bf[4];
#pragma unroll
    for (int mi = 0; mi < 4; ++mi) af[mi] = *(const halfx8*)&As[(wm*64 + mi*16 + l15)*32 + quad*8];
#pragma unroll
    for (int ni = 0; ni < 4; ++ni) bf[ni] = *(const halfx8*)&Bs[(wn*64 + ni*16 + l15)*32 + quad*8];
#pragma unroll
    for (int mi = 0; mi < 4; ++mi)
#pragma unroll
      for (int ni = 0; ni < 4; ++ni)
        acc[mi][ni] = __builtin_amdgcn_mfma_f32_16x16x32_f16(af[mi], bf[ni], acc[mi][ni], 0, 0, 0);
    __syncthreads();
  }
#pragma unroll
  for (int mi = 0; mi < 4; ++mi)
#pragma unroll
    for (int ni = 0; ni < 4; ++ni)
#pragma unroll
      for (int r = 0; r < 4; ++r){
        int m = bm0 + wm*64 + mi*16 + quad*4 + r;
        int n = bn0 + wn*64 + ni*16 + l15;
        float v = acc[mi][ni][r];
        if (OUT_F32) ((float*)Cv)[(size_t)m * ldC + n] = v;
        else         ((unsigned short*)Cv)[(size_t)m * ldC + n] = f2h(v);
      }
}

// ---------------- RMSNorm + RoPE post-process (fp16 in, fp16 out) ----------------
// one wave per (token s, head hh); hh 0..7 = Q, 8..11 = K, 12..15 = V
__global__ __launch_bounds__(256) void qkv_post(const unsigned short* __restrict__ qkvh,
                                                const float* __restrict__ cosb,
                                                const float* __restrict__ sinb,
                                                const float* __restrict__ qnw,
                                                const float* __restrict__ knw,
                                                unsigned short* __restrict__ Qf,
                                                unsigned short* __restrict__ Kf,
                                                unsigned short* __restrict__ Vf){
  int gw   = blockIdx.x * 4 + (threadIdx.x >> 6);
  int lane = threadIdx.x & 63;
  int hh = gw & 15, s = gw >> 4;
  int colbase = (hh < 8) ? hh * 256 : (hh < 12 ? 2048 + (hh - 8) * 256 : 3072 + (hh - 12) * 256);

  ushort4 raw = *(const ushort4*)(qkvh + (size_t)s * 4096 + colbase + lane * 4);
  float x0 = h2f(raw.x), x1 = h2f(raw.y), x2 = h2f(raw.z), x3 = h2f(raw.w);
  float ss = x0*x0 + x1*x1 + x2*x2 + x3*x3;
#pragma unroll
  for (int off = 32; off; off >>= 1) ss += __shfl_xor(ss, off);
  float inv = rsqrtf(ss * (1.0f / 256.0f) + 1e-6f);

  if (hh < 12){
    const float* wp = (hh < 8) ? qnw : knw;
    float4 wv = *(const float4*)(wp + lane * 4);
    float y[4] = { x0*inv*wv.x, x1*inv*wv.y, x2*inv*wv.z, x3*inv*wv.w };
    float4 cv = *(const float4*)(cosb + (size_t)s * 256 + lane * 4);
    float4 sv = *(const float4*)(sinb + (size_t)s * 256 + lane * 4);
    float cj[4] = {cv.x, cv.y, cv.z, cv.w};
    float sj[4] = {sv.x, sv.y, sv.z, sv.w};
    unsigned short oh[4];
#pragma unroll
    for (int j = 0; j < 4; ++j){
      float oth = __shfl_xor(y[j], 32);          // element d +/- 128
      float rot = (lane < 32) ? -oth : oth;      // rot = [-x2, x1]
      oh[j] = f2h(y[j] * cj[j] + rot * sj[j]);
    }
    ushort4 r = make_ushort4(oh[0], oh[1], oh[2], oh[3]);
    if (hh < 8) *(ushort4*)(Qf + (size_t)(hh       * S_LEN + s) * DHEAD + lane * 4) = r;
    else        *(ushort4*)(Kf + (size_t)((hh - 8) * S_LEN + s) * DHEAD + lane * 4) = r;
  } else {
    ushort4 r = make_ushort4(f2h(x0*inv), f2h(x1*inv), f2h(x2*inv), f2h(x3*inv));
    *(ushort4*)(Vf + (size_t)((hh - 12) * S_LEN + s) * DHEAD + lane * 4) = r;
  }
}

// ---------------- V transpose: [kv][s][256] -> [kv][d][4096] ----------------
__global__ __launch_bounds__(256) void transpose_v(const unsigned short* __restrict__ v,
                                                   unsigned short* __restrict__ vt){
  __shared__ unsigned short tile[64][68];
  int kv = blockIdx.z, d0 = blockIdx.x * 64, s0 = blockIdx.y * 64;
  int t = threadIdx.x;
  int r = t >> 4, c4 = (t & 15) * 4;
#pragma unroll
  for (int i = 0; i < 4; ++i){
    int row = r + i * 16;
    ushort4 xx = *(const ushort4*)(v + (size_t)(kv * S_LEN + s0 + row) * DHEAD + d0 + c4);
    tile[row][c4] = xx.x; tile[row][c4+1] = xx.y; tile[row][c4+2] = xx.z; tile[row][c4+3] = xx.w;
  }
  __syncthreads();
#pragma unroll
  for (int i = 0; i < 4; ++i){
    int dr = r + i * 16;
    ushort4 yy = make_ushort4(tile[c4][dr], tile[c4+1][dr], tile[c4+2][dr], tile[c4+3][dr]);
    *(ushort4*)(vt + (size_t)(kv * DHEAD + d0 + dr) * S_LEN + s0 + c4) = yy;
  }
}

// ---------------- sliding-window softcapped flash attention (fp16) ----------------
// 64 queries/block (4 waves x 16 rows), grid (64, 8) = 512 blocks.
__global__ __launch_bounds__(256, 3) void attn_win(const unsigned short* __restrict__ Qg,
                                                   const unsigned short* __restrict__ Kg,
                                                   const unsigned short* __restrict__ Vt,
                                                   unsigned short* __restrict__ Og){
  __shared__ __align__(16) unsigned short Ks[8 * 32 * 32];   // 16 KB
  __shared__ __align__(16) unsigned short Vts[256 * 32];     // 16 KB
  __shared__ __align__(16) unsigned short Pb[4][16 * 48];    //  6 KB

  const int h = blockIdx.y, kv = h >> 1;
  const int q0 = blockIdx.x * 64;
  const int t = threadIdx.x, w = t >> 6, lane = t & 63;
  const int quad = lane >> 4, l15 = lane & 15;
  const int l2 = lane >> 2, g8 = (lane & 3) * 8;
  const int qw0 = q0 + w * 16;

  halfx8 qf[8];
#pragma unroll
  for (int c = 0; c < 8; ++c)
    qf[c] = *(const halfx8*)(Qg + (size_t)(h * S_LEN + qw0 + l15) * DHEAD + c*32 + quad*8);

  const floatx4 zf = {0.f, 0.f, 0.f, 0.f};
  floatx4 oacc[16];
#pragma unroll
  for (int dt = 0; dt < 16; ++dt) oacc[dt] = zf;
  float m_run[4], l_run[4];
#pragma unroll
  for (int r = 0; r < 4; ++r){ m_run[r] = -50.0f; l_run[r] = 0.0f; }  // softcap bounds logits

  int kt_lo = q0 / 32 - 32; if (kt_lo < 0) kt_lo = 0;
  int kt_hi = q0 / 32 + 1;

  for (int kt = kt_lo; kt <= kt_hi; ++kt){
    const int key0 = kt * 32;
#pragma unroll
    for (int j = 0; j < 4; ++j){
      int ch = j * 4 + w;                        // 0..15
      int krow = (ch & 1) * 16 + l2;
      int cb = ch >> 1;
      gld_lds16(Kg + (size_t)(kv * S_LEN + key0 + krow) * DHEAD + cb * 32 + g8, &Ks[ch * 512]);
      int drow = ch * 16 + l2;
      gld_lds16(Vt + (size_t)(kv * DHEAD + drow) * S_LEN + key0 + g8, &Vts[ch * 512]);
    }
    __syncthreads();

    if (key0 <= qw0 + 15 && key0 + 31 >= qw0 - (WIN - 1)){
      // QK^T: 16 MFMA
      floatx4 sc[2];
      sc[0] = zf; sc[1] = zf;
#pragma unroll
      for (int c = 0; c < 8; ++c){
#pragma unroll
        for (int nt = 0; nt < 2; ++nt){
          halfx8 kf = *(const halfx8*)&Ks[c * 1024 + (nt*16 + l15) * 32 + quad * 8];
          sc[nt] = __builtin_amdgcn_mfma_f32_16x16x32_f16(qf[c], kf, sc[nt], 0, 0, 0);
        }
      }
      const bool tfull = (key0 + 31 <= qw0) && (qw0 + 15 - key0 < WIN);
      float x[2][4];
#pragma unroll
      for (int nt = 0; nt < 2; ++nt)
#pragma unroll
        for (int r = 0; r < 4; ++r){
          float v = sc[nt][r];
          float e = __expf(v * 0.04f);           // 50*tanh(v/50) = 50 - 100/(e^{0.04v}+1)
          v = 50.0f - 100.0f / (e + 1.0f);
          if (!tfull){
            int qi = qw0 + quad*4 + r;
            int ki = key0 + nt*16 + l15;
            bool ok = (ki <= qi) && (qi - ki < WIN);
            v = ok ? v : -__builtin_inff();
          }
          x[nt][r] = v;
        }
      // online softmax (rows in 16-lane groups -> xor shuffles 1,2,4,8)
      float alpha[4];
#pragma unroll
      for (int r = 0; r < 4; ++r){
        float tm = fmaxf(x[0][r], x[1][r]);
        tm = fmaxf(tm, __shfl_xor(tm, 1));
        tm = fmaxf(tm, __shfl_xor(tm, 2));
        tm = fmaxf(tm, __shfl_xor(tm, 4));
        tm = fmaxf(tm, __shfl_xor(tm, 8));
        float mo = m_run[r];
        float mn = fmaxf(mo, tm);
        float a = __expf(mo - mn);
        m_run[r] = mn; alpha[r] = a;
        float p0 = __expf(x[0][r] - mn);
        float p1 = __expf(x[1][r] - mn);
        x[0][r] = p0; x[1][r] = p1;
        float ls = p0 + p1;
        ls += __shfl_xor(ls, 1);
        ls += __shfl_xor(ls, 2);
        ls += __shfl_xor(ls, 4);
        ls += __shfl_xor(ls, 8);
        l_run[r] = l_run[r] * a + ls;
      }
      // P: D-layout -> LDS -> A-operand layout
#pragma unroll
      for (int nt = 0; nt < 2; ++nt)
#pragma unroll
        for (int r = 0; r < 4; ++r)
          Pb[w][(quad*4 + r) * 48 + nt*16 + l15] = f2h(x[nt][r]);
      // rescale O
#pragma unroll
      for (int dt = 0; dt < 16; ++dt){
        floatx4 v = oacc[dt];
        v.x *= alpha[0]; v.y *= alpha[1]; v.z *= alpha[2]; v.w *= alpha[3];
        oacc[dt] = v;
      }
      // PV: 16 MFMA
      halfx8 pf = *(const halfx8*)&Pb[w][l15 * 48 + quad * 8];
#pragma unroll
      for (int dt = 0; dt < 16; ++dt){
        halfx8 vf = *(const halfx8*)&Vts[(dt*16 + l15) * 32 + quad * 8];
        oacc[dt] = __builtin_amdgcn_mfma_f32_16x16x32_f16(pf, vf, oacc[dt], 0, 0, 0);
      }
    }
    __syncthreads();
  }
#pragma unroll
  for (int r = 0; r < 4; ++r){
    float rl = 1.0f / l_run[r];
    int srow = qw0 + quad*4 + r;
#pragma unroll
    for (int dt = 0; dt < 16; ++dt)
      Og[(size_t)srow * (NHQ * DHEAD) + h * DHEAD + dt*16 + l15] = f2h(oacc[dt][r] * rl);
  }
}

// ---------------- launch ----------------
extern "C" void kernel_launch(void* const* d_in, const int* in_sizes, int n_in,
                              void* d_out, int out_size, void* d_ws, size_t ws_size,
                              hipStream_t stream){
  const float* hs   = (const float*)d_in[0];
  const float* cosb = (const float*)d_in[1];
  const float* sinb = (const float*)d_in[2];
  // d_in[3] = attention_mask: structure known (0 <= q-k < 1024), never read
  const float* Wq   = (const float*)d_in[4];
  const float* Wk   = (const float*)d_in[5];
  const float* Wv   = (const float*)d_in[6];
  const float* Wo   = (const float*)d_in[7];
  const float* qnw  = (const float*)d_in[8];
  const float* knw  = (const float*)d_in[9];
  float* out = (float*)d_out;

  const size_t MB = 1024ull * 1024ull;
  char* ws = (char*)d_ws;
  unsigned short* h_h   = (unsigned short*)(ws);             // 16 MB [4096][2048] fp16
  unsigned short* w_qkv = (unsigned short*)(ws + 16 * MB);   // 16 MB [4096][2048]
  unsigned short* wo    = (unsigned short*)(ws + 32 * MB);   //  8 MB [2048][2048]
  unsigned short* qkvh  = (unsigned short*)(ws + 40 * MB);   // 32 MB [4096][4096] fp16
  // after QKV GEMM, h_h/w_qkv dead -> Q/K/V live there
  unsigned short* Qf    = (unsigned short*)(ws);             // 16 MB [8][4096][256]
  unsigned short* Kf    = (unsigned short*)(ws + 16 * MB);   //  8 MB [4][4096][256]
  unsigned short* Vf    = (unsigned short*)(ws + 24 * MB);   //  8 MB [4][4096][256]
  // after qkv_post, qkvh dead -> Vt + attention output live there
  unsigned short* vt    = (unsigned short*)(ws + 40 * MB);   //  8 MB [4][256][4096]
  unsigned short* ob    = (unsigned short*)(ws + 48 * MB);   // 16 MB [4096][2048]

  cvt_all<<<20480, 256, 0, stream>>>(hs, Wq, Wk, Wv, Wo, h_h, w_qkv, wo);

  gemm_ht<0><<<dim3(32, 32), 256, 0, stream>>>(h_h, w_qkv, qkvh, 4096, 2048);

  qkv_post<<<16384, 256, 0, stream>>>(qkvh, cosb, sinb, qnw, knw, Qf, Kf, Vf);
  transpose_v<<<dim3(4, 64, 4), 256, 0, stream>>>(Vf, vt);

  attn_win<<<dim3(64, 8), 256, 0, stream>>>(Qf, Kf, vt, ob);

  gemm_ht<1><<<dim3(16, 32), 256, 0, stream>>>(ob, wo, out, 2048, 2048);
}

// Round 6
// 431.092 us; speedup vs baseline: 1.5669x; 1.0304x over previous
//
#include <hip/hip_runtime.h>

#define S_LEN 4096
#define HID   2048
#define NHQ   8
#define NKV   4
#define DHEAD 256
#define WIN   1024

typedef __attribute__((ext_vector_type(4))) float     floatx4;
typedef __attribute__((ext_vector_type(8))) _Float16  halfx8;

__device__ __forceinline__ unsigned short f2h(float f){
  union { _Float16 h; unsigned short u; } cv; cv.h = (_Float16)f; return cv.u;
}
__device__ __forceinline__ float h2f(unsigned short u){
  union { unsigned short u; _Float16 h; } cv; cv.u = u; return (float)cv.h;
}

__device__ __forceinline__ void gld_lds16(const void* g, void* l){
  __builtin_amdgcn_global_load_lds((const __attribute__((address_space(1))) void*)g,
                                   (__attribute__((address_space(3))) void*)l, 16, 0, 0);
}

// ---------------- merged converts (all fp32 -> fp16) ----------------
__global__ __launch_bounds__(256) void cvt_all(const float* __restrict__ hs,
                                               const float* __restrict__ Wq,
                                               const float* __restrict__ Wk,
                                               const float* __restrict__ Wv,
                                               const float* __restrict__ Wo,
                                               unsigned short* __restrict__ h_h,
                                               unsigned short* __restrict__ w_qkv,
                                               unsigned short* __restrict__ wo){
  int bid = blockIdx.x;
  const float* src;
  unsigned short* dst;
  size_t i;
  if (bid < 8192){
    i = ((size_t)bid * 256 + threadIdx.x) * 4;
    src = hs + i; dst = h_h + i;
  } else if (bid < 16384){
    i = ((size_t)(bid - 8192) * 256 + threadIdx.x) * 4;
    int row = (int)(i >> 11), col = (int)(i & 2047);
    src = ((row < 2048) ? (Wq + ((size_t)row << 11))
         : (row < 3072) ? (Wk + ((size_t)(row - 2048) << 11))
                        : (Wv + ((size_t)(row - 3072) << 11))) + col;
    dst = w_qkv + i;
  } else {
    i = ((size_t)(bid - 16384) * 256 + threadIdx.x) * 4;
    src = Wo + i; dst = wo + i;
  }
  float4 v = *(const float4*)src;
  *(ushort4*)dst = make_ushort4(f2h(v.x), f2h(v.y), f2h(v.z), f2h(v.w));
}

// ---------------- fp16 NT GEMM: C = A[M,K] * B[N,K]^T ----------------
template<int OUT_F32>
__global__ __launch_bounds__(256, 2) void gemm_ht(const unsigned short* __restrict__ A,
                                                  const unsigned short* __restrict__ B,
                                                  void* __restrict__ Cv,
                                                  int ldC, int K){
  __shared__ __align__(16) unsigned short As[128 * 32];
  __shared__ __align__(16) unsigned short Bs[128 * 32];
  const int t = threadIdx.x, w = t >> 6, lane = t & 63;
  const int quad = lane >> 4, l15 = lane & 15;
  const int l2 = lane >> 2, g8 = (lane & 3) * 8;
  const int wm = w >> 1, wn = w & 1;
  const int bm0 = blockIdx.y * 128, bn0 = blockIdx.x * 128;

  const floatx4 zf = {0.f, 0.f, 0.f, 0.f};
  floatx4 acc[4][4];
#pragma unroll
  for (int mi = 0; mi < 4; ++mi)
#pragma unroll
    for (int ni = 0; ni < 4; ++ni) acc[mi][ni] = zf;

  for (int k0 = 0; k0 < K; k0 += 32){
#pragma unroll
    for (int j = 0; j < 2; ++j){
      int ch  = j * 4 + w;
      int row = ch * 16 + l2;
      gld_lds16(A + (size_t)(bm0 + row) * K + k0 + g8, &As[ch * 512]);
      gld_lds16(B + (size_t)(bn0 + row) * K + k0 + g8, &Bs[ch * 512]);
    }
    __syncthreads();
    halfx8 af[4], bf[4];
#pragma unroll
    for (int mi = 0; mi < 4; ++mi) af[mi] = *(const halfx8*)&As[(wm*64 + mi*16 + l15)*32 + quad*8];
#pragma unroll
    for (int ni = 0; ni < 4; ++ni) bf[ni] = *(const halfx8*)&Bs[(wn*64 + ni*16 + l15)*32 + quad*8];
#pragma unroll
    for (int mi = 0; mi < 4; ++mi)
#pragma unroll
      for (int ni = 0; ni < 4; ++ni)
        acc[mi][ni] = __builtin_amdgcn_mfma_f32_16x16x32_f16(af[mi], bf[ni], acc[mi][ni], 0, 0, 0);
    __syncthreads();
  }
#pragma unroll
  for (int mi = 0; mi < 4; ++mi)
#pragma unroll
    for (int ni = 0; ni < 4; ++ni)
#pragma unroll
      for (int r = 0; r < 4; ++r){
        int m = bm0 + wm*64 + mi*16 + quad*4 + r;
        int n = bn0 + wn*64 + ni*16 + l15;
        float v = acc[mi][ni][r];
        if (OUT_F32) ((float*)Cv)[(size_t)m * ldC + n] = v;
        else         ((unsigned short*)Cv)[(size_t)m * ldC + n] = f2h(v);
      }
}

// ---------------- RMSNorm + RoPE post-process (fp16 in, fp16 out) ----------------
__global__ __launch_bounds__(256) void qkv_post(const unsigned short* __restrict__ qkvh,
                                                const float* __restrict__ cosb,
                                                const float* __restrict__ sinb,
                                                const float* __restrict__ qnw,
                                                const float* __restrict__ knw,
                                                unsigned short* __restrict__ Qf,
                                                unsigned short* __restrict__ Kf,
                                                unsigned short* __restrict__ Vf){
  int gw   = blockIdx.x * 4 + (threadIdx.x >> 6);
  int lane = threadIdx.x & 63;
  int hh = gw & 15, s = gw >> 4;
  int colbase = (hh < 8) ? hh * 256 : (hh < 12 ? 2048 + (hh - 8) * 256 : 3072 + (hh - 12) * 256);

  ushort4 raw = *(const ushort4*)(qkvh + (size_t)s * 4096 + colbase + lane * 4);
  float x0 = h2f(raw.x), x1 = h2f(raw.y), x2 = h2f(raw.z), x3 = h2f(raw.w);
  float ss = x0*x0 + x1*x1 + x2*x2 + x3*x3;
#pragma unroll
  for (int off = 32; off; off >>= 1) ss += __shfl_xor(ss, off);
  float inv = rsqrtf(ss * (1.0f / 256.0f) + 1e-6f);

  if (hh < 12){
    const float* wp = (hh < 8) ? qnw : knw;
    float4 wv = *(const float4*)(wp + lane * 4);
    float y[4] = { x0*inv*wv.x, x1*inv*wv.y, x2*inv*wv.z, x3*inv*wv.w };
    float4 cv = *(const float4*)(cosb + (size_t)s * 256 + lane * 4);
    float4 sv = *(const float4*)(sinb + (size_t)s * 256 + lane * 4);
    float cj[4] = {cv.x, cv.y, cv.z, cv.w};
    float sj[4] = {sv.x, sv.y, sv.z, sv.w};
    unsigned short oh[4];
#pragma unroll
    for (int j = 0; j < 4; ++j){
      float oth = __shfl_xor(y[j], 32);          // element d +/- 128
      float rot = (lane < 32) ? -oth : oth;      // rot = [-x2, x1]
      oh[j] = f2h(y[j] * cj[j] + rot * sj[j]);
    }
    ushort4 r = make_ushort4(oh[0], oh[1], oh[2], oh[3]);
    if (hh < 8) *(ushort4*)(Qf + (size_t)(hh       * S_LEN + s) * DHEAD + lane * 4) = r;
    else        *(ushort4*)(Kf + (size_t)((hh - 8) * S_LEN + s) * DHEAD + lane * 4) = r;
  } else {
    ushort4 r = make_ushort4(f2h(x0*inv), f2h(x1*inv), f2h(x2*inv), f2h(x3*inv));
    *(ushort4*)(Vf + (size_t)((hh - 12) * S_LEN + s) * DHEAD + lane * 4) = r;
  }
}

// ---------------- V transpose: [kv][s][256] -> [kv][d][4096] ----------------
__global__ __launch_bounds__(256) void transpose_v(const unsigned short* __restrict__ v,
                                                   unsigned short* __restrict__ vt){
  __shared__ unsigned short tile[64][68];
  int kv = blockIdx.z, d0 = blockIdx.x * 64, s0 = blockIdx.y * 64;
  int t = threadIdx.x;
  int r = t >> 4, c4 = (t & 15) * 4;
#pragma unroll
  for (int i = 0; i < 4; ++i){
    int row = r + i * 16;
    ushort4 xx = *(const ushort4*)(v + (size_t)(kv * S_LEN + s0 + row) * DHEAD + d0 + c4);
    tile[row][c4] = xx.x; tile[row][c4+1] = xx.y; tile[row][c4+2] = xx.z; tile[row][c4+3] = xx.w;
  }
  __syncthreads();
#pragma unroll
  for (int i = 0; i < 4; ++i){
    int dr = r + i * 16;
    ushort4 yy = make_ushort4(tile[c4][dr], tile[c4+1][dr], tile[c4+2][dr], tile[c4+3][dr]);
    *(ushort4*)(vt + (size_t)(kv * DHEAD + d0 + dr) * S_LEN + s0 + c4) = yy;
  }
}

// ---------------- sliding-window softcapped flash attention ----------------
// v4: online softmax (R5's fixed-reference underflowed fp16 — row maxima sit ~40
// e-folds below the softcap bound), but keeps R5's double-buffered K/V staging
// with ONE barrier per 32-key tile, defers the l cross-lane reduce to the
// epilogue, and skips the O-rescale wave-wide when no row max grew.
__global__ __launch_bounds__(256, 2) void attn_win(const unsigned short* __restrict__ Qg,
                                                   const unsigned short* __restrict__ Kg,
                                                   const unsigned short* __restrict__ Vt,
                                                   unsigned short* __restrict__ Og){
  __shared__ __align__(16) unsigned short Ks[2][8 * 32 * 32];   // 2x16 KB
  __shared__ __align__(16) unsigned short Vts[2][256 * 32];     // 2x16 KB
  __shared__ __align__(16) unsigned short Pb[4][16 * 48];       //  6 KB

  const int h = blockIdx.y, kv = h >> 1;
  const int q0 = blockIdx.x * 64;
  const int t = threadIdx.x, w = t >> 6, lane = t & 63;
  const int quad = lane >> 4, l15 = lane & 15;
  const int l2 = lane >> 2, g8 = (lane & 3) * 8;
  const int qw0 = q0 + w * 16;

  halfx8 qf[8];
#pragma unroll
  for (int c = 0; c < 8; ++c)
    qf[c] = *(const halfx8*)(Qg + (size_t)(h * S_LEN + qw0 + l15) * DHEAD + c*32 + quad*8);

  const floatx4 zf = {0.f, 0.f, 0.f, 0.f};
  floatx4 oacc[16];
#pragma unroll
  for (int dt = 0; dt < 16; ++dt) oacc[dt] = zf;
  float m_run[4], l_part[4];
#pragma unroll
  for (int r = 0; r < 4; ++r){ m_run[r] = -50.0f; l_part[r] = 0.0f; }  // softcap floor

  int kt_lo = q0 / 32 - 32; if (kt_lo < 0) kt_lo = 0;
  int kt_hi = q0 / 32 + 1;

  const size_t kbase = (size_t)kv * S_LEN * DHEAD;
  const size_t vbase = (size_t)kv * DHEAD * S_LEN;

#define STAGE(KT, B)                                                              \
  {                                                                               \
    const int key0_ = (KT) * 32;                                                  \
    _Pragma("unroll")                                                             \
    for (int j = 0; j < 4; ++j){                                                  \
      int ch = j * 4 + w;                                                         \
      int krow = (ch & 1) * 16 + l2;                                              \
      int cb = ch >> 1;                                                           \
      gld_lds16(Kg + kbase + (size_t)(key0_ + krow) * DHEAD + cb * 32 + g8,       \
                &Ks[B][ch * 512]);                                                \
      int drow = ch * 16 + l2;                                                    \
      gld_lds16(Vt + vbase + (size_t)drow * S_LEN + key0_ + g8,                   \
                &Vts[B][ch * 512]);                                               \
    }                                                                             \
  }

  STAGE(kt_lo, 0);

  for (int kt = kt_lo; kt <= kt_hi; ++kt){
    const int cur = (kt - kt_lo) & 1;
    __syncthreads();                 // drains vmcnt: buf[cur] ready; prev compute done
    if (kt < kt_hi) STAGE(kt + 1, cur ^ 1);

    const int key0 = kt * 32;
    if (key0 <= qw0 + 15 && key0 + 31 >= qw0 - (WIN - 1)){
      // QK^T: 16 MFMA
      floatx4 sc[2];
      sc[0] = zf; sc[1] = zf;
#pragma unroll
      for (int c = 0; c < 8; ++c){
#pragma unroll
        for (int nt = 0; nt < 2; ++nt){
          halfx8 kf = *(const halfx8*)&Ks[cur][c * 1024 + (nt*16 + l15) * 32 + quad * 8];
          sc[nt] = __builtin_amdgcn_mfma_f32_16x16x32_f16(qf[c], kf, sc[nt], 0, 0, 0);
        }
      }
      const bool tfull = (key0 + 31 <= qw0) && (qw0 + 15 - key0 < WIN);
      // softcap: 50*tanh(v/50) = 50 - 100/(e^{0.04v}+1)
      float x[2][4];
#pragma unroll
      for (int nt = 0; nt < 2; ++nt)
#pragma unroll
        for (int r = 0; r < 4; ++r){
          float v = sc[nt][r];
          float e = __expf(v * 0.04f);
          v = 50.0f - 100.0f / (e + 1.0f);
          if (!tfull){
            int qi = qw0 + quad*4 + r;
            int ki = key0 + nt*16 + l15;
            v = ((ki <= qi) && (qi - ki < WIN)) ? v : -__builtin_inff();
          }
          x[nt][r] = v;
        }
      // tile row max (16-lane row groups -> xor shuffles 1,2,4,8)
      float tm[4]; bool grew = false;
#pragma unroll
      for (int r = 0; r < 4; ++r){
        float m2 = fmaxf(x[0][r], x[1][r]);
        m2 = fmaxf(m2, __shfl_xor(m2, 1));
        m2 = fmaxf(m2, __shfl_xor(m2, 2));
        m2 = fmaxf(m2, __shfl_xor(m2, 4));
        m2 = fmaxf(m2, __shfl_xor(m2, 8));
        tm[r] = m2;
        grew = grew || (m2 > m_run[r]);
      }
      if (__any(grew)){              // rescale only when some row max increased
        float al[4];
#pragma unroll
        for (int r = 0; r < 4; ++r){
          float mn = fmaxf(m_run[r], tm[r]);
          al[r] = __expf(m_run[r] - mn);
          m_run[r] = mn;
          l_part[r] *= al[r];
        }
#pragma unroll
        for (int dt = 0; dt < 16; ++dt){
          floatx4 v = oacc[dt];
          v.x *= al[0]; v.y *= al[1]; v.z *= al[2]; v.w *= al[3];
          oacc[dt] = v;
        }
      }
      // p, per-lane l partial, P -> LDS (D-layout -> A-operand layout)
#pragma unroll
      for (int nt = 0; nt < 2; ++nt)
#pragma unroll
        for (int r = 0; r < 4; ++r){
          float p = __expf(x[nt][r] - m_run[r]);
          l_part[r] += p;
          Pb[w][(quad*4 + r) * 48 + nt*16 + l15] = f2h(p);
        }
      // PV: 16 MFMA
      halfx8 pf = *(const halfx8*)&Pb[w][l15 * 48 + quad * 8];
#pragma unroll
      for (int dt = 0; dt < 16; ++dt){
        halfx8 vf = *(const halfx8*)&Vts[cur][(dt*16 + l15) * 32 + quad * 8];
        oacc[dt] = __builtin_amdgcn_mfma_f32_16x16x32_f16(pf, vf, oacc[dt], 0, 0, 0);
      }
    }
  }
#undef STAGE

  // epilogue: reduce l across the 16-lane row groups, normalize, store
#pragma unroll
  for (int r = 0; r < 4; ++r){
    float l = l_part[r];
    l += __shfl_xor(l, 1);
    l += __shfl_xor(l, 2);
    l += __shfl_xor(l, 4);
    l += __shfl_xor(l, 8);
    float rl = 1.0f / l;
    int srow = qw0 + quad*4 + r;
#pragma unroll
    for (int dt = 0; dt < 16; ++dt)
      Og[(size_t)srow * (NHQ * DHEAD) + h * DHEAD + dt*16 + l15] = f2h(oacc[dt][r] * rl);
  }
}

// ---------------- launch ----------------
extern "C" void kernel_launch(void* const* d_in, const int* in_sizes, int n_in,
                              void* d_out, int out_size, void* d_ws, size_t ws_size,
                              hipStream_t stream){
  const float* hs   = (const float*)d_in[0];
  const float* cosb = (const float*)d_in[1];
  const float* sinb = (const float*)d_in[2];
  // d_in[3] = attention_mask: structure known (0 <= q-k < 1024), never read
  const float* Wq   = (const float*)d_in[4];
  const float* Wk   = (const float*)d_in[5];
  const float* Wv   = (const float*)d_in[6];
  const float* Wo   = (const float*)d_in[7];
  const float* qnw  = (const float*)d_in[8];
  const float* knw  = (const float*)d_in[9];
  float* out = (float*)d_out;

  const size_t MB = 1024ull * 1024ull;
  char* ws = (char*)d_ws;
  unsigned short* h_h   = (unsigned short*)(ws);             // 16 MB [4096][2048] fp16
  unsigned short* w_qkv = (unsigned short*)(ws + 16 * MB);   // 16 MB [4096][2048]
  unsigned short* wo    = (unsigned short*)(ws + 32 * MB);   //  8 MB [2048][2048]
  unsigned short* qkvh  = (unsigned short*)(ws + 40 * MB);   // 32 MB [4096][4096] fp16
  // after QKV GEMM, h_h/w_qkv dead -> Q/K/V live there
  unsigned short* Qf    = (unsigned short*)(ws);             // 16 MB [8][4096][256]
  unsigned short* Kf    = (unsigned short*)(ws + 16 * MB);   //  8 MB [4][4096][256]
  unsigned short* Vf    = (unsigned short*)(ws + 24 * MB);   //  8 MB [4][4096][256]
  // after qkv_post, qkvh dead -> Vt + attention output live there
  unsigned short* vt    = (unsigned short*)(ws + 40 * MB);   //  8 MB [4][256][4096]
  unsigned short* ob    = (unsigned short*)(ws + 48 * MB);   // 16 MB [4096][2048]

  cvt_all<<<20480, 256, 0, stream>>>(hs, Wq, Wk, Wv, Wo, h_h, w_qkv, wo);

  gemm_ht<0><<<dim3(32, 32), 256, 0, stream>>>(h_h, w_qkv, qkvh, 4096, 2048);

  qkv_post<<<16384, 256, 0, stream>>>(qkvh, cosb, sinb, qnw, knw, Qf, Kf, Vf);
  transpose_v<<<dim3(4, 64, 4), 256, 0, stream>>>(Vf, vt);

  attn_win<<<dim3(64, 8), 256, 0, stream>>>(Qf, Kf, vt, ob);

  gemm_ht<1><<<dim3(16, 32), 256, 0, stream>>>(ob, wo, out, 2048, 2048);
}

// Round 7
// 404.706 us; speedup vs baseline: 1.6691x; 1.0652x over previous
//
#include <hip/hip_runtime.h>

#define S_LEN 4096
#define HID   2048
#define NHQ   8
#define NKV   4
#define DHEAD 256
#define WIN   1024

typedef __attribute__((ext_vector_type(4))) float     floatx4;
typedef __attribute__((ext_vector_type(8))) _Float16  halfx8;
typedef __attribute__((ext_vector_type(8))) __bf16    bf16x8;

__device__ __forceinline__ unsigned short f2h(float f){
  union { _Float16 h; unsigned short u; } cv; cv.h = (_Float16)f; return cv.u;
}
__device__ __forceinline__ float h2f(unsigned short u){
  union { unsigned short u; _Float16 h; } cv; cv.u = u; return (float)cv.h;
}
__device__ __forceinline__ unsigned short f2bf(float f){
  unsigned int u = __float_as_uint(f);
  u += 0x7FFFu + ((u >> 16) & 1u);           // RNE
  return (unsigned short)(u >> 16);
}

__device__ __forceinline__ void gld_lds16(const void* g, void* l){
  __builtin_amdgcn_global_load_lds((const __attribute__((address_space(1))) void*)g,
                                   (__attribute__((address_space(3))) void*)l, 16, 0, 0);
}

// ---------------- merged converts (all fp32 -> fp16) ----------------
__global__ __launch_bounds__(256) void cvt_all(const float* __restrict__ hs,
                                               const float* __restrict__ Wq,
                                               const float* __restrict__ Wk,
                                               const float* __restrict__ Wv,
                                               const float* __restrict__ Wo,
                                               unsigned short* __restrict__ h_h,
                                               unsigned short* __restrict__ w_qkv,
                                               unsigned short* __restrict__ wo){
  int bid = blockIdx.x;
  const float* src;
  unsigned short* dst;
  size_t i;
  if (bid < 8192){
    i = ((size_t)bid * 256 + threadIdx.x) * 4;
    src = hs + i; dst = h_h + i;
  } else if (bid < 16384){
    i = ((size_t)(bid - 8192) * 256 + threadIdx.x) * 4;
    int row = (int)(i >> 11), col = (int)(i & 2047);
    src = ((row < 2048) ? (Wq + ((size_t)row << 11))
         : (row < 3072) ? (Wk + ((size_t)(row - 2048) << 11))
                        : (Wv + ((size_t)(row - 3072) << 11))) + col;
    dst = w_qkv + i;
  } else {
    i = ((size_t)(bid - 16384) * 256 + threadIdx.x) * 4;
    src = Wo + i; dst = wo + i;
  }
  float4 v = *(const float4*)src;
  *(ushort4*)dst = make_ushort4(f2h(v.x), f2h(v.y), f2h(v.z), f2h(v.w));
}

// ---------------- fp16 NT GEMM: C = A[M,K] * B[N,K]^T ----------------
template<int OUT_F32>
__global__ __launch_bounds__(256, 2) void gemm_ht(const unsigned short* __restrict__ A,
                                                  const unsigned short* __restrict__ B,
                                                  void* __restrict__ Cv,
                                                  int ldC, int K){
  __shared__ __align__(16) unsigned short As[128 * 32];
  __shared__ __align__(16) unsigned short Bs[128 * 32];
  const int t = threadIdx.x, w = t >> 6, lane = t & 63;
  const int quad = lane >> 4, l15 = lane & 15;
  const int l2 = lane >> 2, g8 = (lane & 3) * 8;
  const int wm = w >> 1, wn = w & 1;
  const int bm0 = blockIdx.y * 128, bn0 = blockIdx.x * 128;

  const floatx4 zf = {0.f, 0.f, 0.f, 0.f};
  floatx4 acc[4][4];
#pragma unroll
  for (int mi = 0; mi < 4; ++mi)
#pragma unroll
    for (int ni = 0; ni < 4; ++ni) acc[mi][ni] = zf;

  for (int k0 = 0; k0 < K; k0 += 32){
#pragma unroll
    for (int j = 0; j < 2; ++j){
      int ch  = j * 4 + w;
      int row = ch * 16 + l2;
      gld_lds16(A + (size_t)(bm0 + row) * K + k0 + g8, &As[ch * 512]);
      gld_lds16(B + (size_t)(bn0 + row) * K + k0 + g8, &Bs[ch * 512]);
    }
    __syncthreads();
    halfx8 af[4], bf[4];
#pragma unroll
    for (int mi = 0; mi < 4; ++mi) af[mi] = *(const halfx8*)&As[(wm*64 + mi*16 + l15)*32 + quad*8];
#pragma unroll
    for (int ni = 0; ni < 4; ++ni) bf[ni] = *(const halfx8*)&Bs[(wn*64 + ni*16 + l15)*32 + quad*8];
#pragma unroll
    for (int mi = 0; mi < 4; ++mi)
#pragma unroll
      for (int ni = 0; ni < 4; ++ni)
        acc[mi][ni] = __builtin_amdgcn_mfma_f32_16x16x32_f16(af[mi], bf[ni], acc[mi][ni], 0, 0, 0);
    __syncthreads();
  }
#pragma unroll
  for (int mi = 0; mi < 4; ++mi)
#pragma unroll
    for (int ni = 0; ni < 4; ++ni)
#pragma unroll
      for (int r = 0; r < 4; ++r){
        int m = bm0 + wm*64 + mi*16 + quad*4 + r;
        int n = bn0 + wn*64 + ni*16 + l15;
        float v = acc[mi][ni][r];
        if (OUT_F32) ((float*)Cv)[(size_t)m * ldC + n] = v;
        else         ((unsigned short*)Cv)[(size_t)m * ldC + n] = f2h(v);
      }
}

// ---------------- RMSNorm + RoPE post-process (fp16 in; Q/K fp16 out, V bf16 out) ----------------
__global__ __launch_bounds__(256) void qkv_post(const unsigned short* __restrict__ qkvh,
                                                const float* __restrict__ cosb,
                                                const float* __restrict__ sinb,
                                                const float* __restrict__ qnw,
                                                const float* __restrict__ knw,
                                                unsigned short* __restrict__ Qf,
                                                unsigned short* __restrict__ Kf,
                                                unsigned short* __restrict__ Vf){
  int gw   = blockIdx.x * 4 + (threadIdx.x >> 6);
  int lane = threadIdx.x & 63;
  int hh = gw & 15, s = gw >> 4;
  int colbase = (hh < 8) ? hh * 256 : (hh < 12 ? 2048 + (hh - 8) * 256 : 3072 + (hh - 12) * 256);

  ushort4 raw = *(const ushort4*)(qkvh + (size_t)s * 4096 + colbase + lane * 4);
  float x0 = h2f(raw.x), x1 = h2f(raw.y), x2 = h2f(raw.z), x3 = h2f(raw.w);
  float ss = x0*x0 + x1*x1 + x2*x2 + x3*x3;
#pragma unroll
  for (int off = 32; off; off >>= 1) ss += __shfl_xor(ss, off);
  float inv = rsqrtf(ss * (1.0f / 256.0f) + 1e-6f);

  if (hh < 12){
    const float* wp = (hh < 8) ? qnw : knw;
    float4 wv = *(const float4*)(wp + lane * 4);
    float y[4] = { x0*inv*wv.x, x1*inv*wv.y, x2*inv*wv.z, x3*inv*wv.w };
    float4 cv = *(const float4*)(cosb + (size_t)s * 256 + lane * 4);
    float4 sv = *(const float4*)(sinb + (size_t)s * 256 + lane * 4);
    float cj[4] = {cv.x, cv.y, cv.z, cv.w};
    float sj[4] = {sv.x, sv.y, sv.z, sv.w};
    unsigned short oh[4];
#pragma unroll
    for (int j = 0; j < 4; ++j){
      float oth = __shfl_xor(y[j], 32);          // element d +/- 128
      float rot = (lane < 32) ? -oth : oth;      // rot = [-x2, x1]
      oh[j] = f2h(y[j] * cj[j] + rot * sj[j]);
    }
    ushort4 r = make_ushort4(oh[0], oh[1], oh[2], oh[3]);
    if (hh < 8) *(ushort4*)(Qf + (size_t)(hh       * S_LEN + s) * DHEAD + lane * 4) = r;
    else        *(ushort4*)(Kf + (size_t)((hh - 8) * S_LEN + s) * DHEAD + lane * 4) = r;
  } else {
    // V in bf16 (PV matmul runs bf16 MFMA; bf16 exponent range needed by fixed-ref softmax P)
    ushort4 r = make_ushort4(f2bf(x0*inv), f2bf(x1*inv), f2bf(x2*inv), f2bf(x3*inv));
    *(ushort4*)(Vf + (size_t)((hh - 12) * S_LEN + s) * DHEAD + lane * 4) = r;
  }
}

// ---------------- V transpose: [kv][s][256] -> [kv][d][4096] (dtype-agnostic u16) ----------------
__global__ __launch_bounds__(256) void transpose_v(const unsigned short* __restrict__ v,
                                                   unsigned short* __restrict__ vt){
  __shared__ unsigned short tile[64][68];
  int kv = blockIdx.z, d0 = blockIdx.x * 64, s0 = blockIdx.y * 64;
  int t = threadIdx.x;
  int r = t >> 4, c4 = (t & 15) * 4;
#pragma unroll
  for (int i = 0; i < 4; ++i){
    int row = r + i * 16;
    ushort4 xx = *(const ushort4*)(v + (size_t)(kv * S_LEN + s0 + row) * DHEAD + d0 + c4);
    tile[row][c4] = xx.x; tile[row][c4+1] = xx.y; tile[row][c4+2] = xx.z; tile[row][c4+3] = xx.w;
  }
  __syncthreads();
#pragma unroll
  for (int i = 0; i < 4; ++i){
    int dr = r + i * 16;
    ushort4 yy = make_ushort4(tile[c4][dr], tile[c4+1][dr], tile[c4+2][dr], tile[c4+3][dr]);
    *(ushort4*)(vt + (size_t)(kv * DHEAD + d0 + dr) * S_LEN + s0 + c4) = yy;
  }
}

// ---------------- sliding-window softcapped flash attention ----------------
// v5: FIXED-reference softmax with bf16 P. softcap bounds s to (-50,50); with
// reference m=30, p = exp(s-30) ranges [e^-80, e^20] = [1.8e-35, 4.9e8] — every
// value is a bf16/fp32 NORMAL (R5's fp16-P underflow is structurally impossible,
// no data assumption). No row max, no shuffles, no O-rescale in the loop.
// l accumulates per-lane fp32, reduced once in the epilogue (l >= 1.8e-35 > 0).
// QK^T in fp16 MFMA; PV in bf16 MFMA (P,V bf16). Double-buffered K/V staging,
// one barrier per 32-key tile.
__global__ __launch_bounds__(256, 2) void attn_win(const unsigned short* __restrict__ Qg,
                                                   const unsigned short* __restrict__ Kg,
                                                   const unsigned short* __restrict__ Vt,
                                                   unsigned short* __restrict__ Og){
  __shared__ __align__(16) unsigned short Ks[2][8 * 32 * 32];   // 2x16 KB fp16
  __shared__ __align__(16) unsigned short Vts[2][256 * 32];     // 2x16 KB bf16
  __shared__ __align__(16) unsigned short Pb[4][16 * 48];       //  6 KB bf16

  const int h = blockIdx.y, kv = h >> 1;
  const int q0 = blockIdx.x * 64;
  const int t = threadIdx.x, w = t >> 6, lane = t & 63;
  const int quad = lane >> 4, l15 = lane & 15;
  const int l2 = lane >> 2, g8 = (lane & 3) * 8;
  const int qw0 = q0 + w * 16;

  halfx8 qf[8];
#pragma unroll
  for (int c = 0; c < 8; ++c)
    qf[c] = *(const halfx8*)(Qg + (size_t)(h * S_LEN + qw0 + l15) * DHEAD + c*32 + quad*8);

  const floatx4 zf = {0.f, 0.f, 0.f, 0.f};
  floatx4 oacc[16];
#pragma unroll
  for (int dt = 0; dt < 16; ++dt) oacc[dt] = zf;
  float l_part[4] = {0.f, 0.f, 0.f, 0.f};

  int kt_lo = q0 / 32 - 32; if (kt_lo < 0) kt_lo = 0;
  int kt_hi = q0 / 32 + 1;

  const size_t kbase = (size_t)kv * S_LEN * DHEAD;
  const size_t vbase = (size_t)kv * DHEAD * S_LEN;

#define STAGE(KT, B)                                                              \
  {                                                                               \
    const int key0_ = (KT) * 32;                                                  \
    _Pragma("unroll")                                                             \
    for (int j = 0; j < 4; ++j){                                                  \
      int ch = j * 4 + w;                                                         \
      int krow = (ch & 1) * 16 + l2;                                              \
      int cb = ch >> 1;                                                           \
      gld_lds16(Kg + kbase + (size_t)(key0_ + krow) * DHEAD + cb * 32 + g8,       \
                &Ks[B][ch * 512]);                                                \
      int drow = ch * 16 + l2;                                                    \
      gld_lds16(Vt + vbase + (size_t)drow * S_LEN + key0_ + g8,                   \
                &Vts[B][ch * 512]);                                               \
    }                                                                             \
  }

  STAGE(kt_lo, 0);

  for (int kt = kt_lo; kt <= kt_hi; ++kt){
    const int cur = (kt - kt_lo) & 1;
    __syncthreads();                 // drains vmcnt: buf[cur] ready; prev compute done
    if (kt < kt_hi) STAGE(kt + 1, cur ^ 1);

    const int key0 = kt * 32;
    if (key0 <= qw0 + 15 && key0 + 31 >= qw0 - (WIN - 1)){
      // QK^T: 16 MFMA (fp16)
      floatx4 sc[2];
      sc[0] = zf; sc[1] = zf;
#pragma unroll
      for (int c = 0; c < 8; ++c){
#pragma unroll
        for (int nt = 0; nt < 2; ++nt){
          halfx8 kf = *(const halfx8*)&Ks[cur][c * 1024 + (nt*16 + l15) * 32 + quad * 8];
          sc[nt] = __builtin_amdgcn_mfma_f32_16x16x32_f16(qf[c], kf, sc[nt], 0, 0, 0);
        }
      }
      const bool tfull = (key0 + 31 <= qw0) && (qw0 + 15 - key0 < WIN);
      // fused softcap+exp vs fixed reference 30:
      //   s = 50 - 100/(e^{0.04v}+1);  p = exp(s-30) = exp(20 - 100/(e^{0.04v}+1))
#pragma unroll
      for (int nt = 0; nt < 2; ++nt)
#pragma unroll
        for (int r = 0; r < 4; ++r){
          float v = sc[nt][r];
          float e = __expf(v * 0.04f);
          float p = __expf(20.0f - 100.0f / (e + 1.0f));
          if (!tfull){
            int qi = qw0 + quad*4 + r;
            int ki = key0 + nt*16 + l15;
            p = ((ki <= qi) && (qi - ki < WIN)) ? p : 0.0f;
          }
          l_part[r] += p;
          Pb[w][(quad*4 + r) * 48 + nt*16 + l15] = f2bf(p);
        }
      // PV: 16 MFMA (bf16)
      bf16x8 pf = *(const bf16x8*)&Pb[w][l15 * 48 + quad * 8];
#pragma unroll
      for (int dt = 0; dt < 16; ++dt){
        bf16x8 vf = *(const bf16x8*)&Vts[cur][(dt*16 + l15) * 32 + quad * 8];
        oacc[dt] = __builtin_amdgcn_mfma_f32_16x16x32_bf16(pf, vf, oacc[dt], 0, 0, 0);
      }
    }
  }
#undef STAGE

  // epilogue: reduce l across the 16-lane row groups, normalize, store fp16
#pragma unroll
  for (int r = 0; r < 4; ++r){
    float l = l_part[r];
    l += __shfl_xor(l, 1);
    l += __shfl_xor(l, 2);
    l += __shfl_xor(l, 4);
    l += __shfl_xor(l, 8);
    float rl = 1.0f / l;
    int srow = qw0 + quad*4 + r;
#pragma unroll
    for (int dt = 0; dt < 16; ++dt)
      Og[(size_t)srow * (NHQ * DHEAD) + h * DHEAD + dt*16 + l15] = f2h(oacc[dt][r] * rl);
  }
}

// ---------------- launch ----------------
extern "C" void kernel_launch(void* const* d_in, const int* in_sizes, int n_in,
                              void* d_out, int out_size, void* d_ws, size_t ws_size,
                              hipStream_t stream){
  const float* hs   = (const float*)d_in[0];
  const float* cosb = (const float*)d_in[1];
  const float* sinb = (const float*)d_in[2];
  // d_in[3] = attention_mask: structure known (0 <= q-k < 1024), never read
  const float* Wq   = (const float*)d_in[4];
  const float* Wk   = (const float*)d_in[5];
  const float* Wv   = (const float*)d_in[6];
  const float* Wo   = (const float*)d_in[7];
  const float* qnw  = (const float*)d_in[8];
  const float* knw  = (const float*)d_in[9];
  float* out = (float*)d_out;

  const size_t MB = 1024ull * 1024ull;
  char* ws = (char*)d_ws;
  unsigned short* h_h   = (unsigned short*)(ws);             // 16 MB [4096][2048] fp16
  unsigned short* w_qkv = (unsigned short*)(ws + 16 * MB);   // 16 MB [4096][2048]
  unsigned short* wo    = (unsigned short*)(ws + 32 * MB);   //  8 MB [2048][2048]
  unsigned short* qkvh  = (unsigned short*)(ws + 40 * MB);   // 32 MB [4096][4096] fp16
  // after QKV GEMM, h_h/w_qkv dead -> Q/K/V live there
  unsigned short* Qf    = (unsigned short*)(ws);             // 16 MB [8][4096][256] fp16
  unsigned short* Kf    = (unsigned short*)(ws + 16 * MB);   //  8 MB [4][4096][256] fp16
  unsigned short* Vf    = (unsigned short*)(ws + 24 * MB);   //  8 MB [4][4096][256] bf16
  // after qkv_post, qkvh dead -> Vt + attention output live there
  unsigned short* vt    = (unsigned short*)(ws + 40 * MB);   //  8 MB [4][256][4096] bf16
  unsigned short* ob    = (unsigned short*)(ws + 48 * MB);   // 16 MB [4096][2048] fp16

  cvt_all<<<20480, 256, 0, stream>>>(hs, Wq, Wk, Wv, Wo, h_h, w_qkv, wo);

  gemm_ht<0><<<dim3(32, 32), 256, 0, stream>>>(h_h, w_qkv, qkvh, 4096, 2048);

  qkv_post<<<16384, 256, 0, stream>>>(qkvh, cosb, sinb, qnw, knw, Qf, Kf, Vf);
  transpose_v<<<dim3(4, 64, 4), 256, 0, stream>>>(Vf, vt);

  attn_win<<<dim3(64, 8), 256, 0, stream>>>(Qf, Kf, vt, ob);

  gemm_ht<1><<<dim3(16, 32), 256, 0, stream>>>(ob, wo, out, 2048, 2048);
}